// Round 1
// baseline (2519.680 us; speedup 1.0000x reference)
//
#include <hip/hip_runtime.h>
#include <math.h>

#define G     128
#define NPER  512
#define NTOT  65536
#define E_TOT 1048576
#define EPG   8192
#define INC   100
#define HID   128
#define KP1   410
#define KP2   328
#define KP3   263

// ---------------------------------------------------------------------------
// init: zero bn stats (3 layers x 256), readout accumulator, identity cmap
// ---------------------------------------------------------------------------
__global__ void init_kernel(int* __restrict__ cmap, float* __restrict__ sread,
                            float* __restrict__ bnstat) {
    int t = blockIdx.x * 256 + threadIdx.x;
    if (t < G * NPER) cmap[t] = t & (NPER - 1);
    if (t < G * 256)  sread[t] = 0.f;
    if (t < 768)      bnstat[t] = 0.f;
}

// ---------------------------------------------------------------------------
// GEMM: out[M x 128] = A[M x K] @ W[K x 128]  (+bias, relu if RELU)
// block: 256 thr, tile 128x128, thread 8x8, full K staged in LDS
// ---------------------------------------------------------------------------
template<int K, bool RELU>
__global__ __launch_bounds__(256, 1) void gemm_kernel(
    const float* __restrict__ A, const float* __restrict__ W,
    const float* __restrict__ bias, float* __restrict__ out, int M)
{
    __shared__ float Ws[K * 128];
    __shared__ float As[128 * (K + 1)];
    const int tid  = threadIdx.x;
    const int row0 = blockIdx.x * 128;

    // stage W [K][128] (row-major, float4)
    for (int i = tid; i < K * 32; i += 256)
        ((float4*)Ws)[i] = ((const float4*)W)[i];

    // stage A tile (contiguous float4 stream, scatter into padded rows)
    const float4* A4 = (const float4*)(A + (size_t)row0 * K);
    for (int i = tid; i < K * 32; i += 256) {
        float4 v = A4[i];
        int p = i * 4;
        int r = p / K, k = p - r * K;           As[r * (K + 1) + k] = v.x;
        p++;  r = p / K; k = p - r * K;          As[r * (K + 1) + k] = v.y;
        p++;  r = p / K; k = p - r * K;          As[r * (K + 1) + k] = v.z;
        p++;  r = p / K; k = p - r * K;          As[r * (K + 1) + k] = v.w;
    }
    __syncthreads();

    const int r0 = (tid >> 4) * 8;
    const int c0 = (tid & 15) * 8;
    float acc[8][8];
#pragma unroll
    for (int i = 0; i < 8; ++i)
#pragma unroll
        for (int j = 0; j < 8; ++j) acc[i][j] = 0.f;

    for (int k = 0; k < K; ++k) {
        float4 b0 = *(const float4*)&Ws[k * 128 + c0];
        float4 b1 = *(const float4*)&Ws[k * 128 + c0 + 4];
        float a[8];
#pragma unroll
        for (int i = 0; i < 8; ++i) a[i] = As[(r0 + i) * (K + 1) + k];
#pragma unroll
        for (int i = 0; i < 8; ++i) {
            acc[i][0] += a[i] * b0.x;  acc[i][1] += a[i] * b0.y;
            acc[i][2] += a[i] * b0.z;  acc[i][3] += a[i] * b0.w;
            acc[i][4] += a[i] * b1.x;  acc[i][5] += a[i] * b1.y;
            acc[i][6] += a[i] * b1.z;  acc[i][7] += a[i] * b1.w;
        }
    }

#pragma unroll
    for (int i = 0; i < 8; ++i) {
        int row = row0 + r0 + i;
        float o[8];
#pragma unroll
        for (int j = 0; j < 8; ++j) {
            float v = acc[i][j];
            if (RELU) v = fmaxf(v + bias[c0 + j], 0.f);
            o[j] = v;
        }
        float* po = out + (size_t)row * 128 + c0;
        *(float4*)po       = make_float4(o[0], o[1], o[2], o[3]);
        *(float4*)(po + 4) = make_float4(o[4], o[5], o[6], o[7]);
    }
}

// ---------------------------------------------------------------------------
// gather (GCNConv aggregation): one block per (graph, channel-half)
// LDS accumulator [NCUR x 64] fp32; deg/dinv computed in-block from cmap
// also accumulates BN sum / sumsq into bnstat[256] via global atomics
// ---------------------------------------------------------------------------
template<int NCUR>
__global__ __launch_bounds__(256, 1) void gather_kernel(
    const float* __restrict__ xl, const int* __restrict__ src,
    const int* __restrict__ dst, const int* __restrict__ cmap,
    const float* __restrict__ bvec, float* __restrict__ out,
    float* __restrict__ bnstat)
{
    __shared__ float acc[NCUR * 64];
    __shared__ int   cmap_s[NPER];
    __shared__ int   cnt_s[NCUR];
    __shared__ float dinv_s[NCUR];
    __shared__ float red_s[256];

    const int g = blockIdx.x, half = blockIdx.y;
    const int tid = threadIdx.x, lane = tid & 63, w = tid >> 6;
    const int ebase = g * EPG;
    const int obase = g * NPER;
    const int nodebase = g * NCUR;

    for (int i = tid; i < NPER; i += 256) cmap_s[i] = cmap[obase + i];
    for (int i = tid; i < NCUR; i += 256) cnt_s[i] = 0;
    __syncthreads();

    // count valid in-edges per current dst
    for (int e = tid; e < EPG; e += 256) {
        int sl = cmap_s[src[ebase + e] - obase];
        int dl = cmap_s[dst[ebase + e] - obase];
        if ((sl | dl) >= 0) atomicAdd(&cnt_s[dl], 1);
    }
    __syncthreads();
    for (int i = tid; i < NCUR; i += 256)
        dinv_s[i] = rsqrtf((float)(cnt_s[i] + 1));
    for (int i = tid; i < NCUR * 16; i += 256)
        ((float4*)acc)[i] = make_float4(0.f, 0.f, 0.f, 0.f);
    __syncthreads();

    const int c = half * 64 + lane;
    const int EPW = EPG / 4;     // edges per wave
    for (int b0 = 0; b0 < EPW; b0 += 64) {
        int e  = ebase + w * EPW + b0 + lane;
        int sl = cmap_s[src[e] - obase];
        int dl = cmap_s[dst[e] - obase];
        int pk; float cf;
        if ((sl | dl) >= 0) { pk = sl | (dl << 16); cf = dinv_s[sl] * dinv_s[dl]; }
        else                { pk = -1;              cf = 0.f; }
#pragma unroll
        for (int j = 0; j < 64; ++j) {
            int pkj = __shfl(pk, j);
            if (pkj < 0) continue;                 // wave-uniform branch
            float cfj = __shfl(cf, j);
            int slj = pkj & 0xFFFF, dlj = pkj >> 16;
            float v = cfj * xl[(nodebase + slj) * 128 + c];
            atomicAdd(&acc[dlj * 64 + lane], v);
        }
    }
    __syncthreads();

    // epilogue: + self-loop + bias, write out, BN partials
    float bsum = 0.f, bsq = 0.f;
    float bc = bvec[c];
    for (int d = w; d < NCUR; d += 4) {
        float x  = xl[(nodebase + d) * 128 + c];
        float dv = dinv_s[d];
        float o  = bc + dv * dv * x + acc[d * 64 + lane];
        out[(nodebase + d) * 128 + c] = o;
        bsum += o; bsq += o * o;
    }
    red_s[tid] = bsum; __syncthreads();
    if (tid < 64) {
        float s = red_s[tid] + red_s[64 + tid] + red_s[128 + tid] + red_s[192 + tid];
        atomicAdd(&bnstat[half * 64 + tid], s);
    }
    __syncthreads();
    red_s[tid] = bsq; __syncthreads();
    if (tid < 64) {
        float q = red_s[tid] + red_s[64 + tid] + red_s[128 + tid] + red_s[192 + tid];
        atomicAdd(&bnstat[128 + half * 64 + tid], q);
    }
}

// ---------------------------------------------------------------------------
// BN finalize + att normalization -> coefs = [a(128), c(128), attn(128)]
// ---------------------------------------------------------------------------
__global__ void bnfin_kernel(const float* __restrict__ stat, float n,
                             const float* __restrict__ gamma,
                             const float* __restrict__ beta,
                             const float* __restrict__ att,
                             float* __restrict__ coefs)
{
    __shared__ float r[128];
    int t = threadIdx.x;
    float av = att[t];
    r[t] = av * av;
    __syncthreads();
    for (int s = 64; s > 0; s >>= 1) {
        if (t < s) r[t] += r[t + s];
        __syncthreads();
    }
    float norm = sqrtf(r[0]);
    float mu   = stat[t] / n;
    float var  = stat[128 + t] / n - mu * mu;
    float inv  = rsqrtf(var + 1e-5f);
    float a    = gamma[t] * inv;
    coefs[t]        = a;
    coefs[128 + t]  = beta[t] - mu * a;
    coefs[256 + t]  = av / norm;
}

// ---------------------------------------------------------------------------
// pool: per-graph scores -> bitonic top-k -> gated new_x, readout(+=sread),
// cmap update.  One block per graph.
// ---------------------------------------------------------------------------
template<int NCUR, int KK>
__global__ __launch_bounds__(256, 1) void pool_kernel(
    const float* __restrict__ gcn, const float* __restrict__ coefs,
    float* __restrict__ newx, int* __restrict__ cmap,
    float* __restrict__ sread)
{
    __shared__ float score_s[NCUR];
    __shared__ unsigned long long comp_s[512];
    __shared__ int   o2n_s[NCUR];
    __shared__ float red_s[512];

    const int g = blockIdx.x, tid = threadIdx.x, lane = tid & 63, w = tid >> 6;
    const int nb = g * NCUR;
    const float a0 = coefs[lane],       a1 = coefs[64 + lane];
    const float c0 = coefs[128 + lane], c1 = coefs[192 + lane];
    const float t0 = coefs[256 + lane], t1 = coefs[320 + lane];

    // scores: one wave per node
    for (int i = w; i < NCUR; i += 4) {
        const float* row = gcn + (size_t)(nb + i) * 128;
        float h0 = fmaxf(a0 * row[lane] + c0, 0.f);
        float h1 = fmaxf(a1 * row[64 + lane] + c1, 0.f);
        float p  = h0 * t0 + h1 * t1;
#pragma unroll
        for (int off = 32; off > 0; off >>= 1) p += __shfl_down(p, off);
        if (lane == 0) score_s[i] = tanhf(p);
    }
    __syncthreads();

    // composite keys: (ordered-float key << 32) | (0xFFFFFFFF - idx)
    for (int i = tid; i < 512; i += 256) {
        unsigned long long cmp = 0ull;
        if (i < NCUR) {
            unsigned u   = __float_as_uint(score_s[i]);
            unsigned key = (u & 0x80000000u) ? ~u : (u | 0x80000000u);
            cmp = ((unsigned long long)key << 32) |
                  (unsigned long long)(0xFFFFFFFFu - (unsigned)i);
        }
        comp_s[i] = cmp;
    }
    __syncthreads();

    // bitonic sort ascending, 512 elems / 256 threads
    for (int size = 2; size <= 512; size <<= 1) {
        for (int stride = size >> 1; stride > 0; stride >>= 1) {
            int i = 2 * tid - (tid & (stride - 1));
            int j = i + stride;
            bool up = ((i & size) == 0);
            unsigned long long x = comp_s[i], y = comp_s[j];
            if ((x > y) == up) { comp_s[i] = y; comp_s[j] = x; }
            __syncthreads();
        }
    }

    // gating + write new_x + readout partials (top KK = last KK ascending)
    float mx0 = -1e30f, mx1 = -1e30f, sm0 = 0.f, sm1 = 0.f;
    for (int j2 = w; j2 < KK; j2 += 4) {
        int old = (int)(0xFFFFFFFFu -
                        (unsigned)(comp_s[511 - j2] & 0xFFFFFFFFull));
        float s = score_s[old];
        const float* row = gcn + (size_t)(nb + old) * 128;
        float h0 = fmaxf(a0 * row[lane] + c0, 0.f) * s;
        float h1 = fmaxf(a1 * row[64 + lane] + c1, 0.f) * s;
        float* orow = newx + (size_t)(g * KK + j2) * 128;
        orow[lane]      = h0;
        orow[64 + lane] = h1;
        mx0 = fmaxf(mx0, h0); mx1 = fmaxf(mx1, h1);
        sm0 += h0; sm1 += h1;
    }
    red_s[w * 128 + lane]      = mx0;
    red_s[w * 128 + 64 + lane] = mx1;
    __syncthreads();
    if (tid < 128) {
        float m = fmaxf(fmaxf(red_s[tid], red_s[128 + tid]),
                        fmaxf(red_s[256 + tid], red_s[384 + tid]));
        sread[g * 256 + tid] += m;
    }
    __syncthreads();
    red_s[w * 128 + lane]      = sm0;
    red_s[w * 128 + 64 + lane] = sm1;
    __syncthreads();
    if (tid < 128) {
        float sm = red_s[tid] + red_s[128 + tid] + red_s[256 + tid] + red_s[384 + tid];
        sread[g * 256 + 128 + tid] += sm * (1.0f / KK);
    }

    // cmap update: orig -> new current id (or -1)
    for (int i = tid; i < NCUR; i += 256) o2n_s[i] = -1;
    __syncthreads();
    for (int j2 = tid; j2 < KK; j2 += 256) {
        int old = (int)(0xFFFFFFFFu -
                        (unsigned)(comp_s[511 - j2] & 0xFFFFFFFFull));
        o2n_s[old] = j2;
    }
    __syncthreads();
    for (int o = tid; o < NPER; o += 256) {
        int m = cmap[g * NPER + o];
        if (m >= 0) cmap[g * NPER + o] = o2n_s[m];
    }
}

// ---------------------------------------------------------------------------
// final MLP: out[g,2] = relu(s @ Wl1 + bl1) @ Wl2 + bl2
// ---------------------------------------------------------------------------
__global__ void final_kernel(const float* __restrict__ sread,
                             const float* __restrict__ Wl1,
                             const float* __restrict__ bl1,
                             const float* __restrict__ Wl2,
                             const float* __restrict__ bl2,
                             float* __restrict__ out)
{
    __shared__ float s_s[256];
    __shared__ float hid_s[128];
    int g = blockIdx.x, t = threadIdx.x;
    s_s[t]       = sread[g * 256 + t];
    s_s[128 + t] = sread[g * 256 + 128 + t];
    __syncthreads();
    float acc = bl1[t];
    for (int i = 0; i < 256; ++i) acc += s_s[i] * Wl1[i * 128 + t];
    hid_s[t] = fmaxf(acc, 0.f);
    __syncthreads();
    if (t < 2) {
        float o = bl2[t];
        for (int j = 0; j < 128; ++j) o += hid_s[j] * Wl2[j * 2 + t];
        out[g * 2 + t] = o;
    }
}

// ---------------------------------------------------------------------------
extern "C" void kernel_launch(void* const* d_in, const int* in_sizes, int n_in,
                              void* d_out, int out_size, void* d_ws, size_t ws_size,
                              hipStream_t stream)
{
    const float* x    = (const float*)d_in[0];
    const int*   ei   = (const int*)d_in[1];
    const float* Wp   = (const float*)d_in[3];
    const float* bp   = (const float*)d_in[4];
    const float* W1   = (const float*)d_in[5];
    const float* b1   = (const float*)d_in[6];
    const float* g1   = (const float*)d_in[7];
    const float* be1  = (const float*)d_in[8];
    const float* att1 = (const float*)d_in[9];
    const float* W2   = (const float*)d_in[10];
    const float* b2   = (const float*)d_in[11];
    const float* g2   = (const float*)d_in[12];
    const float* be2  = (const float*)d_in[13];
    const float* att2 = (const float*)d_in[14];
    const float* W3   = (const float*)d_in[15];
    const float* b3   = (const float*)d_in[16];
    const float* g3   = (const float*)d_in[17];
    const float* be3  = (const float*)d_in[18];
    const float* att3 = (const float*)d_in[19];
    const float* Wl1  = (const float*)d_in[20];
    const float* bl1  = (const float*)d_in[21];
    const float* Wl2  = (const float*)d_in[22];
    const float* bl2  = (const float*)d_in[23];
    float* out = (float*)d_out;

    const int* srcp = ei;
    const int* dstp = ei + E_TOT;

    char* ws = (char*)d_ws;
    float* bufA   = (float*)ws;                       // 33,554,432 B
    float* bufB   = (float*)(ws + 33554432);          // 33,554,432 B
    int*   cmap   = (int*)  (ws + 67108864);          //    262,144 B
    float* bnstat = (float*)(ws + 67371008);          //      3,072 B
    float* coefs  = (float*)(ws + 67374080);          //      1,536 B
    float* sread  = (float*)(ws + 67375616);          //    131,072 B

    init_kernel<<<256, 256, 0, stream>>>(cmap, sread, bnstat);

    // h0 = relu(x @ Wp + bp)
    gemm_kernel<INC, true><<<512, 256, 0, stream>>>(x, Wp, bp, bufA, NTOT);

    // ---- layer 1 ----
    gemm_kernel<128, false><<<512, 256, 0, stream>>>(bufA, W1, nullptr, bufB, NTOT);
    gather_kernel<512><<<dim3(G, 2), 256, 0, stream>>>(bufB, srcp, dstp, cmap, b1, bufA, bnstat);
    bnfin_kernel<<<1, 128, 0, stream>>>(bnstat, (float)NTOT, g1, be1, att1, coefs);
    pool_kernel<512, KP1><<<G, 256, 0, stream>>>(bufA, coefs, bufB, cmap, sread);

    // ---- layer 2 ----  (nodes: G*KP1 = 52480)
    gemm_kernel<128, false><<<410, 256, 0, stream>>>(bufB, W2, nullptr, bufA, G * KP1);
    gather_kernel<KP1><<<dim3(G, 2), 256, 0, stream>>>(bufA, srcp, dstp, cmap, b2, bufB, bnstat + 256);
    bnfin_kernel<<<1, 128, 0, stream>>>(bnstat + 256, (float)(G * KP1), g2, be2, att2, coefs);
    pool_kernel<KP1, KP2><<<G, 256, 0, stream>>>(bufB, coefs, bufA, cmap, sread);

    // ---- layer 3 ----  (nodes: G*KP2 = 41984)
    gemm_kernel<128, false><<<328, 256, 0, stream>>>(bufA, W3, nullptr, bufB, G * KP2);
    gather_kernel<KP2><<<dim3(G, 2), 256, 0, stream>>>(bufB, srcp, dstp, cmap, b3, bufA, bnstat + 512);
    bnfin_kernel<<<1, 128, 0, stream>>>(bnstat + 512, (float)(G * KP2), g3, be3, att3, coefs);
    pool_kernel<KP2, KP3><<<G, 256, 0, stream>>>(bufA, coefs, bufB, cmap, sread);

    final_kernel<<<G, 128, 0, stream>>>(sread, Wl1, bl1, Wl2, bl2, out);
}

// Round 2
// 1100.633 us; speedup vs baseline: 2.2893x; 2.2893x over previous
//
#include <hip/hip_runtime.h>
#include <math.h>

#define G     128
#define NPER  512
#define NTOT  65536
#define E_TOT 1048576
#define EPG   8192
#define INC   100
#define HID   128
#define KP1   410
#define KP2   328
#define KP3   263

// ---------------------------------------------------------------------------
// init: zero bn stats (3 layers x 256), readout accumulator, identity cmap
// ---------------------------------------------------------------------------
__global__ void init_kernel(int* __restrict__ cmap, float* __restrict__ sread,
                            float* __restrict__ bnstat) {
    int t = blockIdx.x * 256 + threadIdx.x;
    if (t < G * NPER) cmap[t] = t & (NPER - 1);
    if (t < G * 256)  sread[t] = 0.f;
    if (t < 768)      bnstat[t] = 0.f;
}

// ---------------------------------------------------------------------------
// GEMM: out[M x 128] = A[M x K] @ W[K x 128]  (+bias, relu if RELU)
// block: 256 thr, tile 128x128, thread 8x8, full K staged in LDS
// ---------------------------------------------------------------------------
template<int K, bool RELU>
__global__ __launch_bounds__(256, 1) void gemm_kernel(
    const float* __restrict__ A, const float* __restrict__ W,
    const float* __restrict__ bias, float* __restrict__ out, int M)
{
    __shared__ float Ws[K * 128];
    __shared__ float As[128 * (K + 1)];
    const int tid  = threadIdx.x;
    const int row0 = blockIdx.x * 128;

    // stage W [K][128] (row-major, float4)
    for (int i = tid; i < K * 32; i += 256)
        ((float4*)Ws)[i] = ((const float4*)W)[i];

    // stage A tile (contiguous float4 stream, scatter into padded rows)
    const float4* A4 = (const float4*)(A + (size_t)row0 * K);
    for (int i = tid; i < K * 32; i += 256) {
        float4 v = A4[i];
        int p = i * 4;
        int r = p / K, k = p - r * K;           As[r * (K + 1) + k] = v.x;
        p++;  r = p / K; k = p - r * K;          As[r * (K + 1) + k] = v.y;
        p++;  r = p / K; k = p - r * K;          As[r * (K + 1) + k] = v.z;
        p++;  r = p / K; k = p - r * K;          As[r * (K + 1) + k] = v.w;
    }
    __syncthreads();

    const int r0 = (tid >> 4) * 8;
    const int c0 = (tid & 15) * 8;
    float acc[8][8];
#pragma unroll
    for (int i = 0; i < 8; ++i)
#pragma unroll
        for (int j = 0; j < 8; ++j) acc[i][j] = 0.f;

    for (int k = 0; k < K; ++k) {
        float4 b0 = *(const float4*)&Ws[k * 128 + c0];
        float4 b1 = *(const float4*)&Ws[k * 128 + c0 + 4];
        float a[8];
#pragma unroll
        for (int i = 0; i < 8; ++i) a[i] = As[(r0 + i) * (K + 1) + k];
#pragma unroll
        for (int i = 0; i < 8; ++i) {
            acc[i][0] += a[i] * b0.x;  acc[i][1] += a[i] * b0.y;
            acc[i][2] += a[i] * b0.z;  acc[i][3] += a[i] * b0.w;
            acc[i][4] += a[i] * b1.x;  acc[i][5] += a[i] * b1.y;
            acc[i][6] += a[i] * b1.z;  acc[i][7] += a[i] * b1.w;
        }
    }

#pragma unroll
    for (int i = 0; i < 8; ++i) {
        int row = row0 + r0 + i;
        float o[8];
#pragma unroll
        for (int j = 0; j < 8; ++j) {
            float v = acc[i][j];
            if (RELU) v = fmaxf(v + bias[c0 + j], 0.f);
            o[j] = v;
        }
        float* po = out + (size_t)row * 128 + c0;
        *(float4*)po       = make_float4(o[0], o[1], o[2], o[3]);
        *(float4*)(po + 4) = make_float4(o[4], o[5], o[6], o[7]);
    }
}

// ---------------------------------------------------------------------------
// gather (GCNConv aggregation), CSR-in-LDS design:
//   one block per (graph, channel-half), 512 threads = 8 waves.
//   phase 1: count valid in-edges per dst (LDS atomics) -> deg, dinv
//   phase 2: exclusive prefix sum (wave shfl-scan) -> rowptr
//   phase 3: scatter src local ids (uint16) into CSR
//   phase 4: one WAVE per dst node, lanes = 64 channels, register acc,
//            wave-uniform LDS broadcasts, coalesced 256B xl loads.
//   epilogue: self-loop + bias, BN sum/sumsq partials -> global atomics
// ---------------------------------------------------------------------------
template<int NCUR>
__global__ __launch_bounds__(512, 1) void gather_kernel(
    const float* __restrict__ xl, const int* __restrict__ src,
    const int* __restrict__ dst, const int* __restrict__ cmap,
    const float* __restrict__ bvec, float* __restrict__ out,
    float* __restrict__ bnstat)
{
    __shared__ unsigned short csr_s[EPG];    // 16 KB
    __shared__ int   cmap_s[NPER];           // 2 KB
    __shared__ int   cnt_s[512];             // 2 KB (zero-padded past NCUR)
    __shared__ int   rowptr_s[513];
    __shared__ int   wo_s[512];
    __shared__ float dinv_s[512];
    __shared__ int   chunksum_s[9];
    __shared__ float red_s[512];

    const int g = blockIdx.x, half = blockIdx.y;
    const int tid = threadIdx.x, lane = tid & 63, w = tid >> 6;
    const int ebase = g * EPG;
    const int obase = g * NPER;
    const int nb    = g * NCUR;

    for (int i = tid; i < NPER; i += 512) cmap_s[i] = cmap[obase + i];
    cnt_s[tid] = 0;
    __syncthreads();

    // phase 1: count valid in-edges per current dst
    for (int e = tid; e < EPG; e += 512) {
        int sl = cmap_s[src[ebase + e] - obase];
        int dl = cmap_s[dst[ebase + e] - obase];
        if ((sl | dl) >= 0) atomicAdd(&cnt_s[dl], 1);
    }
    __syncthreads();

    // phase 2: exclusive prefix sum over 512 counters (8 chunks of 64)
    {
        int i = w * 64 + lane;
        int orig = cnt_s[i];
        int x = orig;
#pragma unroll
        for (int d = 1; d < 64; d <<= 1) {
            int y = __shfl_up(x, d);
            if (lane >= d) x += y;
        }
        if (lane == 63) chunksum_s[w] = x;
        __syncthreads();
        if (tid == 0) {
            int acc = 0;
#pragma unroll
            for (int k2 = 0; k2 < 8; ++k2) {
                int t = chunksum_s[k2]; chunksum_s[k2] = acc; acc += t;
            }
            chunksum_s[8] = acc;
        }
        __syncthreads();
        int excl = x - orig + chunksum_s[w];
        rowptr_s[i] = excl;
        wo_s[i]     = excl;
        if (i < NCUR) dinv_s[i] = rsqrtf((float)(orig + 1));
        if (tid == 0) rowptr_s[512] = chunksum_s[8];
    }
    __syncthreads();

    // phase 3: scatter src local ids into CSR
    for (int e = tid; e < EPG; e += 512) {
        int sl = cmap_s[src[ebase + e] - obase];
        int dl = cmap_s[dst[ebase + e] - obase];
        if ((sl | dl) >= 0) {
            int pos = atomicAdd(&wo_s[dl], 1);
            csr_s[pos] = (unsigned short)sl;
        }
    }
    __syncthreads();

    // phase 4: one wave per dst, lanes = channels
    const int   c  = half * 64 + lane;
    const float bc = bvec[c];
    float bsum = 0.f, bsq = 0.f;
    for (int d = w; d < NCUR; d += 8) {
        const int beg = rowptr_s[d], end = rowptr_s[d + 1];
        float acc = 0.f;
        for (int i = beg; i < end; ++i) {
            int sl = csr_s[i];                      // wave-uniform broadcast
            acc += dinv_s[sl] * xl[(size_t)(nb + sl) * 128 + c];
        }
        float dv    = dinv_s[d];
        float xself = xl[(size_t)(nb + d) * 128 + c];
        float o = bc + dv * acc + dv * dv * xself;
        out[(size_t)(nb + d) * 128 + c] = o;
        bsum += o; bsq += o * o;
    }

    // BN partials
    red_s[tid] = bsum; __syncthreads();
    if (tid < 64) {
        float s = 0.f;
#pragma unroll
        for (int k2 = 0; k2 < 8; ++k2) s += red_s[tid + 64 * k2];
        atomicAdd(&bnstat[half * 64 + tid], s);
    }
    __syncthreads();
    red_s[tid] = bsq; __syncthreads();
    if (tid < 64) {
        float q = 0.f;
#pragma unroll
        for (int k2 = 0; k2 < 8; ++k2) q += red_s[tid + 64 * k2];
        atomicAdd(&bnstat[128 + half * 64 + tid], q);
    }
}

// ---------------------------------------------------------------------------
// BN finalize + att normalization -> coefs = [a(128), c(128), attn(128)]
// ---------------------------------------------------------------------------
__global__ void bnfin_kernel(const float* __restrict__ stat, float n,
                             const float* __restrict__ gamma,
                             const float* __restrict__ beta,
                             const float* __restrict__ att,
                             float* __restrict__ coefs)
{
    __shared__ float r[128];
    int t = threadIdx.x;
    float av = att[t];
    r[t] = av * av;
    __syncthreads();
    for (int s = 64; s > 0; s >>= 1) {
        if (t < s) r[t] += r[t + s];
        __syncthreads();
    }
    float norm = sqrtf(r[0]);
    float mu   = stat[t] / n;
    float var  = stat[128 + t] / n - mu * mu;
    float inv  = rsqrtf(var + 1e-5f);
    float a    = gamma[t] * inv;
    coefs[t]        = a;
    coefs[128 + t]  = beta[t] - mu * a;
    coefs[256 + t]  = av / norm;
}

// ---------------------------------------------------------------------------
// pool: per-graph scores -> bitonic top-k -> gated new_x, readout(+=sread),
// cmap update.  One block per graph.
// ---------------------------------------------------------------------------
template<int NCUR, int KK>
__global__ __launch_bounds__(256, 1) void pool_kernel(
    const float* __restrict__ gcn, const float* __restrict__ coefs,
    float* __restrict__ newx, int* __restrict__ cmap,
    float* __restrict__ sread)
{
    __shared__ float score_s[NCUR];
    __shared__ unsigned long long comp_s[512];
    __shared__ int   o2n_s[NCUR];
    __shared__ float red_s[512];

    const int g = blockIdx.x, tid = threadIdx.x, lane = tid & 63, w = tid >> 6;
    const int nb = g * NCUR;
    const float a0 = coefs[lane],       a1 = coefs[64 + lane];
    const float c0 = coefs[128 + lane], c1 = coefs[192 + lane];
    const float t0 = coefs[256 + lane], t1 = coefs[320 + lane];

    // scores: one wave per node
    for (int i = w; i < NCUR; i += 4) {
        const float* row = gcn + (size_t)(nb + i) * 128;
        float h0 = fmaxf(a0 * row[lane] + c0, 0.f);
        float h1 = fmaxf(a1 * row[64 + lane] + c1, 0.f);
        float p  = h0 * t0 + h1 * t1;
#pragma unroll
        for (int off = 32; off > 0; off >>= 1) p += __shfl_down(p, off);
        if (lane == 0) score_s[i] = tanhf(p);
    }
    __syncthreads();

    // composite keys: (ordered-float key << 32) | (0xFFFFFFFF - idx)
    for (int i = tid; i < 512; i += 256) {
        unsigned long long cmp = 0ull;
        if (i < NCUR) {
            unsigned u   = __float_as_uint(score_s[i]);
            unsigned key = (u & 0x80000000u) ? ~u : (u | 0x80000000u);
            cmp = ((unsigned long long)key << 32) |
                  (unsigned long long)(0xFFFFFFFFu - (unsigned)i);
        }
        comp_s[i] = cmp;
    }
    __syncthreads();

    // bitonic sort ascending, 512 elems / 256 threads
    for (int size = 2; size <= 512; size <<= 1) {
        for (int stride = size >> 1; stride > 0; stride >>= 1) {
            int i = 2 * tid - (tid & (stride - 1));
            int j = i + stride;
            bool up = ((i & size) == 0);
            unsigned long long x = comp_s[i], y = comp_s[j];
            if ((x > y) == up) { comp_s[i] = y; comp_s[j] = x; }
            __syncthreads();
        }
    }

    // gating + write new_x + readout partials (top KK = last KK ascending)
    float mx0 = -1e30f, mx1 = -1e30f, sm0 = 0.f, sm1 = 0.f;
    for (int j2 = w; j2 < KK; j2 += 4) {
        int old = (int)(0xFFFFFFFFu -
                        (unsigned)(comp_s[511 - j2] & 0xFFFFFFFFull));
        float s = score_s[old];
        const float* row = gcn + (size_t)(nb + old) * 128;
        float h0 = fmaxf(a0 * row[lane] + c0, 0.f) * s;
        float h1 = fmaxf(a1 * row[64 + lane] + c1, 0.f) * s;
        float* orow = newx + (size_t)(g * KK + j2) * 128;
        orow[lane]      = h0;
        orow[64 + lane] = h1;
        mx0 = fmaxf(mx0, h0); mx1 = fmaxf(mx1, h1);
        sm0 += h0; sm1 += h1;
    }
    red_s[w * 128 + lane]      = mx0;
    red_s[w * 128 + 64 + lane] = mx1;
    __syncthreads();
    if (tid < 128) {
        float m = fmaxf(fmaxf(red_s[tid], red_s[128 + tid]),
                        fmaxf(red_s[256 + tid], red_s[384 + tid]));
        sread[g * 256 + tid] += m;
    }
    __syncthreads();
    red_s[w * 128 + lane]      = sm0;
    red_s[w * 128 + 64 + lane] = sm1;
    __syncthreads();
    if (tid < 128) {
        float sm = red_s[tid] + red_s[128 + tid] + red_s[256 + tid] + red_s[384 + tid];
        sread[g * 256 + 128 + tid] += sm * (1.0f / KK);
    }

    // cmap update: orig -> new current id (or -1)
    for (int i = tid; i < NCUR; i += 256) o2n_s[i] = -1;
    __syncthreads();
    for (int j2 = tid; j2 < KK; j2 += 256) {
        int old = (int)(0xFFFFFFFFu -
                        (unsigned)(comp_s[511 - j2] & 0xFFFFFFFFull));
        o2n_s[old] = j2;
    }
    __syncthreads();
    for (int o = tid; o < NPER; o += 256) {
        int m = cmap[g * NPER + o];
        if (m >= 0) cmap[g * NPER + o] = o2n_s[m];
    }
}

// ---------------------------------------------------------------------------
// final MLP: out[g,2] = relu(s @ Wl1 + bl1) @ Wl2 + bl2
// ---------------------------------------------------------------------------
__global__ void final_kernel(const float* __restrict__ sread,
                             const float* __restrict__ Wl1,
                             const float* __restrict__ bl1,
                             const float* __restrict__ Wl2,
                             const float* __restrict__ bl2,
                             float* __restrict__ out)
{
    __shared__ float s_s[256];
    __shared__ float hid_s[128];
    int g = blockIdx.x, t = threadIdx.x;
    s_s[t]       = sread[g * 256 + t];
    s_s[128 + t] = sread[g * 256 + 128 + t];
    __syncthreads();
    float acc = bl1[t];
    for (int i = 0; i < 256; ++i) acc += s_s[i] * Wl1[i * 128 + t];
    hid_s[t] = fmaxf(acc, 0.f);
    __syncthreads();
    if (t < 2) {
        float o = bl2[t];
        for (int j = 0; j < 128; ++j) o += hid_s[j] * Wl2[j * 2 + t];
        out[g * 2 + t] = o;
    }
}

// ---------------------------------------------------------------------------
extern "C" void kernel_launch(void* const* d_in, const int* in_sizes, int n_in,
                              void* d_out, int out_size, void* d_ws, size_t ws_size,
                              hipStream_t stream)
{
    const float* x    = (const float*)d_in[0];
    const int*   ei   = (const int*)d_in[1];
    const float* Wp   = (const float*)d_in[3];
    const float* bp   = (const float*)d_in[4];
    const float* W1   = (const float*)d_in[5];
    const float* b1   = (const float*)d_in[6];
    const float* g1   = (const float*)d_in[7];
    const float* be1  = (const float*)d_in[8];
    const float* att1 = (const float*)d_in[9];
    const float* W2   = (const float*)d_in[10];
    const float* b2   = (const float*)d_in[11];
    const float* g2   = (const float*)d_in[12];
    const float* be2  = (const float*)d_in[13];
    const float* att2 = (const float*)d_in[14];
    const float* W3   = (const float*)d_in[15];
    const float* b3   = (const float*)d_in[16];
    const float* g3   = (const float*)d_in[17];
    const float* be3  = (const float*)d_in[18];
    const float* att3 = (const float*)d_in[19];
    const float* Wl1  = (const float*)d_in[20];
    const float* bl1  = (const float*)d_in[21];
    const float* Wl2  = (const float*)d_in[22];
    const float* bl2  = (const float*)d_in[23];
    float* out = (float*)d_out;

    const int* srcp = ei;
    const int* dstp = ei + E_TOT;

    char* ws = (char*)d_ws;
    float* bufA   = (float*)ws;                       // 33,554,432 B
    float* bufB   = (float*)(ws + 33554432);          // 33,554,432 B
    int*   cmap   = (int*)  (ws + 67108864);          //    262,144 B
    float* bnstat = (float*)(ws + 67371008);          //      3,072 B
    float* coefs  = (float*)(ws + 67374080);          //      1,536 B
    float* sread  = (float*)(ws + 67375616);          //    131,072 B

    init_kernel<<<256, 256, 0, stream>>>(cmap, sread, bnstat);

    // h0 = relu(x @ Wp + bp)
    gemm_kernel<INC, true><<<512, 256, 0, stream>>>(x, Wp, bp, bufA, NTOT);

    // ---- layer 1 ----
    gemm_kernel<128, false><<<512, 256, 0, stream>>>(bufA, W1, nullptr, bufB, NTOT);
    gather_kernel<512><<<dim3(G, 2), 512, 0, stream>>>(bufB, srcp, dstp, cmap, b1, bufA, bnstat);
    bnfin_kernel<<<1, 128, 0, stream>>>(bnstat, (float)NTOT, g1, be1, att1, coefs);
    pool_kernel<512, KP1><<<G, 256, 0, stream>>>(bufA, coefs, bufB, cmap, sread);

    // ---- layer 2 ----  (nodes: G*KP1 = 52480)
    gemm_kernel<128, false><<<410, 256, 0, stream>>>(bufB, W2, nullptr, bufA, G * KP1);
    gather_kernel<KP1><<<dim3(G, 2), 512, 0, stream>>>(bufA, srcp, dstp, cmap, b2, bufB, bnstat + 256);
    bnfin_kernel<<<1, 128, 0, stream>>>(bnstat + 256, (float)(G * KP1), g2, be2, att2, coefs);
    pool_kernel<KP1, KP2><<<G, 256, 0, stream>>>(bufB, coefs, bufA, cmap, sread);

    // ---- layer 3 ----  (nodes: G*KP2 = 41984)
    gemm_kernel<128, false><<<328, 256, 0, stream>>>(bufA, W3, nullptr, bufB, G * KP2);
    gather_kernel<KP2><<<dim3(G, 2), 512, 0, stream>>>(bufB, srcp, dstp, cmap, b3, bufA, bnstat + 512);
    bnfin_kernel<<<1, 128, 0, stream>>>(bnstat + 512, (float)(G * KP2), g3, be3, att3, coefs);
    pool_kernel<KP2, KP3><<<G, 256, 0, stream>>>(bufA, coefs, bufB, cmap, sread);

    final_kernel<<<G, 128, 0, stream>>>(sread, Wl1, bl1, Wl2, bl2, out);
}

// Round 3
// 780.370 us; speedup vs baseline: 3.2288x; 1.4104x over previous
//
#include <hip/hip_runtime.h>
#include <math.h>

#define G     128
#define NPER  512
#define NTOT  65536
#define E_TOT 1048576
#define EPG   8192
#define INC   100
#define HID   128
#define KP1   410
#define KP2   328
#define KP3   263

// ---------------------------------------------------------------------------
// init: identity cmap (short), zero sread + bnpart
// ---------------------------------------------------------------------------
__global__ void init_kernel(short* __restrict__ cmap, float* __restrict__ sread,
                            float* __restrict__ bnpart) {
    int t = blockIdx.x * 256 + threadIdx.x;
    if (t < NTOT) cmap[t] = (short)(t & (NPER - 1));
    if (t < G * 256) { sread[t] = 0.f; bnpart[t] = 0.f; }
}

// ---------------------------------------------------------------------------
// GEMM: out[M x 128] = A[M x K] @ W[K x 128]  (+bias, relu if RELU)
// block: 256 thr, tile 128x128, thread 8x8, full K staged in LDS
// ---------------------------------------------------------------------------
template<int K, bool RELU>
__global__ __launch_bounds__(256, 1) void gemm_kernel(
    const float* __restrict__ A, const float* __restrict__ W,
    const float* __restrict__ bias, float* __restrict__ out, int M)
{
    __shared__ float Ws[K * 128];
    __shared__ float As[128 * (K + 1)];
    const int tid  = threadIdx.x;
    const int row0 = blockIdx.x * 128;

    for (int i = tid; i < K * 32; i += 256)
        ((float4*)Ws)[i] = ((const float4*)W)[i];

    const float4* A4 = (const float4*)(A + (size_t)row0 * K);
    for (int i = tid; i < K * 32; i += 256) {
        float4 v = A4[i];
        int p = i * 4;
        int r = p / K, k = p - r * K;           As[r * (K + 1) + k] = v.x;
        p++;  r = p / K; k = p - r * K;          As[r * (K + 1) + k] = v.y;
        p++;  r = p / K; k = p - r * K;          As[r * (K + 1) + k] = v.z;
        p++;  r = p / K; k = p - r * K;          As[r * (K + 1) + k] = v.w;
    }
    __syncthreads();

    const int r0 = (tid >> 4) * 8;
    const int c0 = (tid & 15) * 8;
    float acc[8][8];
#pragma unroll
    for (int i = 0; i < 8; ++i)
#pragma unroll
        for (int j = 0; j < 8; ++j) acc[i][j] = 0.f;

    for (int k = 0; k < K; ++k) {
        float4 b0 = *(const float4*)&Ws[k * 128 + c0];
        float4 b1 = *(const float4*)&Ws[k * 128 + c0 + 4];
        float a[8];
#pragma unroll
        for (int i = 0; i < 8; ++i) a[i] = As[(r0 + i) * (K + 1) + k];
#pragma unroll
        for (int i = 0; i < 8; ++i) {
            acc[i][0] += a[i] * b0.x;  acc[i][1] += a[i] * b0.y;
            acc[i][2] += a[i] * b0.z;  acc[i][3] += a[i] * b0.w;
            acc[i][4] += a[i] * b1.x;  acc[i][5] += a[i] * b1.y;
            acc[i][6] += a[i] * b1.z;  acc[i][7] += a[i] * b1.w;
        }
    }

#pragma unroll
    for (int i = 0; i < 8; ++i) {
        int row = row0 + r0 + i;
        float o[8];
#pragma unroll
        for (int j = 0; j < 8; ++j) {
            float v = acc[i][j];
            if (RELU) v = fmaxf(v + bias[c0 + j], 0.f);
            o[j] = v;
        }
        float* po = out + (size_t)row * 128 + c0;
        *(float4*)po       = make_float4(o[0], o[1], o[2], o[3]);
        *(float4*)(po + 4) = make_float4(o[4], o[5], o[6], o[7]);
    }
}

// ---------------------------------------------------------------------------
// gather (GCNConv aggregation), chunked CSR-in-LDS:
//   grid (G, 8), 256 threads (4 waves). Block (g,s) owns dst chunk
//   [s*CHUNK, min((s+1)*CHUNK, NCUR)).
//   pass 1: count ALL valid in-edges per dst (LDS atomics) -> dinv[NCUR]
//   pass 2: scatter THIS chunk's edges into LDS CSR (ushort src ids)
//   compute: one wave per dst (strided), lanes = 64 float2 channels,
//            register float2 accumulate, unroll-4 for MLP.
//   BN partials -> per-graph global atomics (8-way contention).
// ---------------------------------------------------------------------------
template<int NCUR>
__global__ __launch_bounds__(256, 4) void gather_kernel(
    const float* __restrict__ xs, const int* __restrict__ src,
    const int* __restrict__ dst, const short* __restrict__ cmap,
    const float* __restrict__ bvec, float* __restrict__ out,
    float* __restrict__ bnpart)
{
    constexpr int CHUNK = (NCUR + 7) / 8;
    constexpr int CSRCAP = 3072;
    __shared__ short cmap_s[NPER];
    __shared__ int   cnt_s[NCUR];
    __shared__ float dinv_s[NCUR];
    __shared__ int   rowptr_s[CHUNK + 1];
    __shared__ int   wo_s[CHUNK];
    __shared__ unsigned short csr_s[CSRCAP];
    __shared__ float red_s[512];

    const int g = blockIdx.x, s = blockIdx.y;
    const int tid = threadIdx.x, lane = tid & 63, w = tid >> 6;
    const int ebase = g * EPG, obase = g * NPER, nb = g * NCUR;
    const int d0 = s * CHUNK;
    const int d1 = (d0 + CHUNK < NCUR) ? d0 + CHUNK : NCUR;
    const int len = d1 - d0;

    for (int i = tid; i < NPER; i += 256) cmap_s[i] = cmap[obase + i];
    for (int i = tid; i < NCUR; i += 256) cnt_s[i] = 0;
    __syncthreads();

    // pass 1: full-graph valid in-degree
    for (int e = tid; e < EPG; e += 256) {
        int sl = cmap_s[src[ebase + e] - obase];
        int dl = cmap_s[dst[ebase + e] - obase];
        if ((sl | dl) >= 0) atomicAdd(&cnt_s[dl], 1);
    }
    __syncthreads();

    for (int i = tid; i < NCUR; i += 256)
        dinv_s[i] = rsqrtf((float)(cnt_s[i] + 1));

    // chunk-local exclusive prefix (wave 0; len <= 64)
    if (tid < 64) {
        int v = (tid < len) ? cnt_s[d0 + tid] : 0;
        int x = v;
#pragma unroll
        for (int dlt = 1; dlt < 64; dlt <<= 1) {
            int y = __shfl_up(x, dlt);
            if (tid >= dlt) x += y;
        }
        int excl = x - v;
        if (tid < len) { rowptr_s[tid] = excl; wo_s[tid] = excl; }
        if (tid == 63) rowptr_s[len] = x;   // pads are 0 -> lane63 incl = total
    }
    __syncthreads();

    // pass 2: scatter this chunk's edges
    for (int e = tid; e < EPG; e += 256) {
        int sl = cmap_s[src[ebase + e] - obase];
        int dl = cmap_s[dst[ebase + e] - obase];
        if ((sl | dl) >= 0) {
            int r = dl - d0;
            if ((unsigned)r < (unsigned)len) {
                int pos = atomicAdd(&wo_s[r], 1);
                if (pos < CSRCAP) csr_s[pos] = (unsigned short)sl;
            }
        }
    }
    __syncthreads();

    // compute: wave per dst, full 128-channel row as float2
    const float2* x2 = (const float2*)xs;
    float2* o2p = (float2*)out;
    const float2 b2 = ((const float2*)bvec)[lane];
    float2 sum = make_float2(0.f, 0.f), sq = make_float2(0.f, 0.f);

    for (int d = d0 + w; d < d1; d += 4) {
        const int beg = rowptr_s[d - d0], end = rowptr_s[d - d0 + 1];
        const float dv = dinv_s[d];
        float2 xv = x2[(size_t)(nb + d) * 64 + lane];
        float2 acc = make_float2(dv * xv.x, dv * xv.y);
#pragma unroll 4
        for (int i = beg; i < end; ++i) {
            int sl = csr_s[i];                    // wave-uniform broadcast
            float ws_ = dinv_s[sl];               // wave-uniform broadcast
            float2 v = x2[(size_t)(nb + sl) * 64 + lane];
            acc.x += ws_ * v.x; acc.y += ws_ * v.y;
        }
        float2 o = make_float2(b2.x + dv * acc.x, b2.y + dv * acc.y);
        o2p[(size_t)(nb + d) * 64 + lane] = o;
        sum.x += o.x; sum.y += o.y;
        sq.x  += o.x * o.x; sq.y += o.y * o.y;
    }

    // BN partials: cross-wave reduce then per-graph atomics
    float2* red2 = (float2*)red_s;
    red2[tid] = sum; __syncthreads();
    if (tid < 64) {
        float2 a = red2[tid], b_ = red2[tid + 64],
               c = red2[tid + 128], d_ = red2[tid + 192];
        atomicAdd(&bnpart[g * 256 + 2 * tid],     a.x + b_.x + c.x + d_.x);
        atomicAdd(&bnpart[g * 256 + 2 * tid + 1], a.y + b_.y + c.y + d_.y);
    }
    __syncthreads();
    red2[tid] = sq; __syncthreads();
    if (tid < 64) {
        float2 a = red2[tid], b_ = red2[tid + 64],
               c = red2[tid + 128], d_ = red2[tid + 192];
        atomicAdd(&bnpart[g * 256 + 128 + 2 * tid],     a.x + b_.x + c.x + d_.x);
        atomicAdd(&bnpart[g * 256 + 128 + 2 * tid + 1], a.y + b_.y + c.y + d_.y);
    }
}

// ---------------------------------------------------------------------------
// BN finalize (reduce per-graph partials) + att norm -> coefs[384]
// ---------------------------------------------------------------------------
__global__ void bnfin_kernel(const float* __restrict__ bnpart, float n,
                             const float* __restrict__ gamma,
                             const float* __restrict__ beta,
                             const float* __restrict__ att,
                             float* __restrict__ coefs)
{
    __shared__ float r[128];
    int t = threadIdx.x;
    float s = 0.f, q = 0.f;
#pragma unroll 4
    for (int g = 0; g < G; ++g) {
        s += bnpart[g * 256 + t];
        q += bnpart[g * 256 + 128 + t];
    }
    float av = att[t];
    r[t] = av * av;
    __syncthreads();
    for (int st = 64; st > 0; st >>= 1) {
        if (t < st) r[t] += r[t + st];
        __syncthreads();
    }
    float norm = sqrtf(r[0]);
    float mu   = s / n;
    float var  = q / n - mu * mu;
    float inv  = rsqrtf(var + 1e-5f);
    float a    = gamma[t] * inv;
    coefs[t]        = a;
    coefs[128 + t]  = beta[t] - mu * a;
    coefs[256 + t]  = av / norm;
}

// ---------------------------------------------------------------------------
// pool: per-graph scores -> bitonic top-k -> gated new_x, readout(+=sread),
// cmap update (short), zero bnpart slice for next layer. One block per graph.
// ---------------------------------------------------------------------------
template<int NCUR, int KK>
__global__ __launch_bounds__(256, 1) void pool_kernel(
    const float* __restrict__ gcn, const float* __restrict__ coefs,
    float* __restrict__ newx, short* __restrict__ cmap,
    float* __restrict__ sread, float* __restrict__ bnpart)
{
    __shared__ float score_s[NCUR];
    __shared__ unsigned long long comp_s[512];
    __shared__ int   o2n_s[NCUR];
    __shared__ float red_s[512];

    const int g = blockIdx.x, tid = threadIdx.x, lane = tid & 63, w = tid >> 6;
    const int nb = g * NCUR;
    const float a0 = coefs[lane],       a1 = coefs[64 + lane];
    const float c0 = coefs[128 + lane], c1 = coefs[192 + lane];
    const float t0 = coefs[256 + lane], t1 = coefs[320 + lane];

    // scores: one wave per node
    for (int i = w; i < NCUR; i += 4) {
        const float* row = gcn + (size_t)(nb + i) * 128;
        float h0 = fmaxf(a0 * row[lane] + c0, 0.f);
        float h1 = fmaxf(a1 * row[64 + lane] + c1, 0.f);
        float p  = h0 * t0 + h1 * t1;
#pragma unroll
        for (int off = 32; off > 0; off >>= 1) p += __shfl_down(p, off);
        if (lane == 0) score_s[i] = tanhf(p);
    }
    __syncthreads();

    for (int i = tid; i < 512; i += 256) {
        unsigned long long cmp = 0ull;
        if (i < NCUR) {
            unsigned u   = __float_as_uint(score_s[i]);
            unsigned key = (u & 0x80000000u) ? ~u : (u | 0x80000000u);
            cmp = ((unsigned long long)key << 32) |
                  (unsigned long long)(0xFFFFFFFFu - (unsigned)i);
        }
        comp_s[i] = cmp;
    }
    __syncthreads();

    for (int size = 2; size <= 512; size <<= 1) {
        for (int stride = size >> 1; stride > 0; stride >>= 1) {
            int i = 2 * tid - (tid & (stride - 1));
            int j = i + stride;
            bool up = ((i & size) == 0);
            unsigned long long x = comp_s[i], y = comp_s[j];
            if ((x > y) == up) { comp_s[i] = y; comp_s[j] = x; }
            __syncthreads();
        }
    }

    float mx0 = -1e30f, mx1 = -1e30f, sm0 = 0.f, sm1 = 0.f;
    for (int j2 = w; j2 < KK; j2 += 4) {
        int old = (int)(0xFFFFFFFFu -
                        (unsigned)(comp_s[511 - j2] & 0xFFFFFFFFull));
        float s = score_s[old];
        const float* row = gcn + (size_t)(nb + old) * 128;
        float h0 = fmaxf(a0 * row[lane] + c0, 0.f) * s;
        float h1 = fmaxf(a1 * row[64 + lane] + c1, 0.f) * s;
        float* orow = newx + (size_t)(g * KK + j2) * 128;
        orow[lane]      = h0;
        orow[64 + lane] = h1;
        mx0 = fmaxf(mx0, h0); mx1 = fmaxf(mx1, h1);
        sm0 += h0; sm1 += h1;
    }
    red_s[w * 128 + lane]      = mx0;
    red_s[w * 128 + 64 + lane] = mx1;
    __syncthreads();
    if (tid < 128) {
        float m = fmaxf(fmaxf(red_s[tid], red_s[128 + tid]),
                        fmaxf(red_s[256 + tid], red_s[384 + tid]));
        sread[g * 256 + tid] += m;
    }
    __syncthreads();
    red_s[w * 128 + lane]      = sm0;
    red_s[w * 128 + 64 + lane] = sm1;
    __syncthreads();
    if (tid < 128) {
        float sm = red_s[tid] + red_s[128 + tid] + red_s[256 + tid] + red_s[384 + tid];
        sread[g * 256 + 128 + tid] += sm * (1.0f / KK);
    }

    // cmap update
    for (int i = tid; i < NCUR; i += 256) o2n_s[i] = -1;
    __syncthreads();
    for (int j2 = tid; j2 < KK; j2 += 256) {
        int old = (int)(0xFFFFFFFFu -
                        (unsigned)(comp_s[511 - j2] & 0xFFFFFFFFull));
        o2n_s[old] = j2;
    }
    __syncthreads();
    for (int o = tid; o < NPER; o += 256) {
        int m = cmap[g * NPER + o];
        if (m >= 0) cmap[g * NPER + o] = (short)o2n_s[m];
    }

    // zero this graph's bnpart slice for next layer
    bnpart[g * 256 + tid] = 0.f;
    bnpart[g * 256 + 128 + ((tid < 128) ? tid : tid - 128)] = 0.f;  // covers all 256
}

// ---------------------------------------------------------------------------
// final MLP: out[g,2] = relu(s @ Wl1 + bl1) @ Wl2 + bl2
// ---------------------------------------------------------------------------
__global__ void final_kernel(const float* __restrict__ sread,
                             const float* __restrict__ Wl1,
                             const float* __restrict__ bl1,
                             const float* __restrict__ Wl2,
                             const float* __restrict__ bl2,
                             float* __restrict__ out)
{
    __shared__ float s_s[256];
    __shared__ float hid_s[128];
    int g = blockIdx.x, t = threadIdx.x;
    s_s[t]       = sread[g * 256 + t];
    s_s[128 + t] = sread[g * 256 + 128 + t];
    __syncthreads();
    float acc = bl1[t];
    for (int i = 0; i < 256; ++i) acc += s_s[i] * Wl1[i * 128 + t];
    hid_s[t] = fmaxf(acc, 0.f);
    __syncthreads();
    if (t < 2) {
        float o = bl2[t];
        for (int j = 0; j < 128; ++j) o += hid_s[j] * Wl2[j * 2 + t];
        out[g * 2 + t] = o;
    }
}

// ---------------------------------------------------------------------------
extern "C" void kernel_launch(void* const* d_in, const int* in_sizes, int n_in,
                              void* d_out, int out_size, void* d_ws, size_t ws_size,
                              hipStream_t stream)
{
    const float* x    = (const float*)d_in[0];
    const int*   ei   = (const int*)d_in[1];
    const float* Wp   = (const float*)d_in[3];
    const float* bp   = (const float*)d_in[4];
    const float* W1   = (const float*)d_in[5];
    const float* b1   = (const float*)d_in[6];
    const float* g1   = (const float*)d_in[7];
    const float* be1  = (const float*)d_in[8];
    const float* att1 = (const float*)d_in[9];
    const float* W2   = (const float*)d_in[10];
    const float* b2   = (const float*)d_in[11];
    const float* g2   = (const float*)d_in[12];
    const float* be2  = (const float*)d_in[13];
    const float* att2 = (const float*)d_in[14];
    const float* W3   = (const float*)d_in[15];
    const float* b3   = (const float*)d_in[16];
    const float* g3   = (const float*)d_in[17];
    const float* be3  = (const float*)d_in[18];
    const float* att3 = (const float*)d_in[19];
    const float* Wl1  = (const float*)d_in[20];
    const float* bl1  = (const float*)d_in[21];
    const float* Wl2  = (const float*)d_in[22];
    const float* bl2  = (const float*)d_in[23];
    float* out = (float*)d_out;

    const int* srcp = ei;
    const int* dstp = ei + E_TOT;

    char* ws = (char*)d_ws;
    float* bufA   = (float*)ws;                       // 33,554,432 B
    float* bufB   = (float*)(ws + 33554432);          // 33,554,432 B
    float* bnpart = (float*)(ws + 67108864);          //    131,072 B
    short* cmap   = (short*)(ws + 67239936);          //    131,072 B
    float* sread  = (float*)(ws + 67371008);          //    131,072 B
    float* coefs  = (float*)(ws + 67502080);          //      1,536 B

    init_kernel<<<256, 256, 0, stream>>>(cmap, sread, bnpart);

    // h0 = relu(x @ Wp + bp)
    gemm_kernel<INC, true><<<512, 256, 0, stream>>>(x, Wp, bp, bufA, NTOT);

    // ---- layer 1 ----
    gemm_kernel<128, false><<<512, 256, 0, stream>>>(bufA, W1, nullptr, bufB, NTOT);
    gather_kernel<512><<<dim3(G, 8), 256, 0, stream>>>(bufB, srcp, dstp, cmap, b1, bufA, bnpart);
    bnfin_kernel<<<1, 128, 0, stream>>>(bnpart, (float)NTOT, g1, be1, att1, coefs);
    pool_kernel<512, KP1><<<G, 256, 0, stream>>>(bufA, coefs, bufB, cmap, sread, bnpart);

    // ---- layer 2 ----  (nodes: G*KP1 = 52480)
    gemm_kernel<128, false><<<410, 256, 0, stream>>>(bufB, W2, nullptr, bufA, G * KP1);
    gather_kernel<KP1><<<dim3(G, 8), 256, 0, stream>>>(bufA, srcp, dstp, cmap, b2, bufB, bnpart);
    bnfin_kernel<<<1, 128, 0, stream>>>(bnpart, (float)(G * KP1), g2, be2, att2, coefs);
    pool_kernel<KP1, KP2><<<G, 256, 0, stream>>>(bufB, coefs, bufA, cmap, sread, bnpart);

    // ---- layer 3 ----  (nodes: G*KP2 = 41984)
    gemm_kernel<128, false><<<328, 256, 0, stream>>>(bufA, W3, nullptr, bufB, G * KP2);
    gather_kernel<KP2><<<dim3(G, 8), 256, 0, stream>>>(bufB, srcp, dstp, cmap, b3, bufA, bnpart);
    bnfin_kernel<<<1, 128, 0, stream>>>(bnpart, (float)(G * KP2), g3, be3, att3, coefs);
    pool_kernel<KP2, KP3><<<G, 256, 0, stream>>>(bufA, coefs, bufB, cmap, sread, bnpart);

    final_kernel<<<G, 128, 0, stream>>>(sread, Wl1, bl1, Wl2, bl2, out);
}

// Round 4
// 622.304 us; speedup vs baseline: 4.0490x; 1.2540x over previous
//
#include <hip/hip_runtime.h>
#include <math.h>

#define G     128
#define NPER  512
#define NTOT  65536
#define E_TOT 1048576
#define EPG   8192
#define INC   100
#define HID   128
#define KP1   410
#define KP2   328
#define KP3   263

// ---------------------------------------------------------------------------
// init: identity cmap (short), zero sread + bnpart
// ---------------------------------------------------------------------------
__global__ void init_kernel(short* __restrict__ cmap, float* __restrict__ sread,
                            float* __restrict__ bnpart) {
    int t = blockIdx.x * 256 + threadIdx.x;
    if (t < NTOT) cmap[t] = (short)(t & (NPER - 1));
    if (t < G * 256) { sread[t] = 0.f; bnpart[t] = 0.f; }
}

// ---------------------------------------------------------------------------
// GEMM: out[M x 128] = A[M x K] @ W[K x 128]  (+bias, relu if RELU)
// block: 256 thr, tile 128x128, thread 8x8, full K staged in LDS
// ---------------------------------------------------------------------------
template<int K, bool RELU>
__global__ __launch_bounds__(256, 1) void gemm_kernel(
    const float* __restrict__ A, const float* __restrict__ W,
    const float* __restrict__ bias, float* __restrict__ out, int M)
{
    __shared__ float Ws[K * 128];
    __shared__ float As[128 * (K + 1)];
    const int tid  = threadIdx.x;
    const int row0 = blockIdx.x * 128;

    for (int i = tid; i < K * 32; i += 256)
        ((float4*)Ws)[i] = ((const float4*)W)[i];

    const float4* A4 = (const float4*)(A + (size_t)row0 * K);
    for (int i = tid; i < K * 32; i += 256) {
        float4 v = A4[i];
        int p = i * 4;
        int r = p / K, k = p - r * K;           As[r * (K + 1) + k] = v.x;
        p++;  r = p / K; k = p - r * K;          As[r * (K + 1) + k] = v.y;
        p++;  r = p / K; k = p - r * K;          As[r * (K + 1) + k] = v.z;
        p++;  r = p / K; k = p - r * K;          As[r * (K + 1) + k] = v.w;
    }
    __syncthreads();

    const int r0 = (tid >> 4) * 8;
    const int c0 = (tid & 15) * 8;
    float acc[8][8];
#pragma unroll
    for (int i = 0; i < 8; ++i)
#pragma unroll
        for (int j = 0; j < 8; ++j) acc[i][j] = 0.f;

    for (int k = 0; k < K; ++k) {
        float4 b0 = *(const float4*)&Ws[k * 128 + c0];
        float4 b1 = *(const float4*)&Ws[k * 128 + c0 + 4];
        float a[8];
#pragma unroll
        for (int i = 0; i < 8; ++i) a[i] = As[(r0 + i) * (K + 1) + k];
#pragma unroll
        for (int i = 0; i < 8; ++i) {
            acc[i][0] += a[i] * b0.x;  acc[i][1] += a[i] * b0.y;
            acc[i][2] += a[i] * b0.z;  acc[i][3] += a[i] * b0.w;
            acc[i][4] += a[i] * b1.x;  acc[i][5] += a[i] * b1.y;
            acc[i][6] += a[i] * b1.z;  acc[i][7] += a[i] * b1.w;
        }
    }

#pragma unroll
    for (int i = 0; i < 8; ++i) {
        int row = row0 + r0 + i;
        float o[8];
#pragma unroll
        for (int j = 0; j < 8; ++j) {
            float v = acc[i][j];
            if (RELU) v = fmaxf(v + bias[c0 + j], 0.f);
            o[j] = v;
        }
        float* po = out + (size_t)row * 128 + c0;
        *(float4*)po       = make_float4(o[0], o[1], o[2], o[3]);
        *(float4*)(po + 4) = make_float4(o[4], o[5], o[6], o[7]);
    }
}

// ---------------------------------------------------------------------------
// gather (GCNConv aggregation), chunked CSR-in-LDS (unchanged from R2)
// ---------------------------------------------------------------------------
template<int NCUR>
__global__ __launch_bounds__(256, 4) void gather_kernel(
    const float* __restrict__ xs, const int* __restrict__ src,
    const int* __restrict__ dst, const short* __restrict__ cmap,
    const float* __restrict__ bvec, float* __restrict__ out,
    float* __restrict__ bnpart)
{
    constexpr int CHUNK = (NCUR + 7) / 8;
    constexpr int CSRCAP = 3072;
    __shared__ short cmap_s[NPER];
    __shared__ int   cnt_s[NCUR];
    __shared__ float dinv_s[NCUR];
    __shared__ int   rowptr_s[CHUNK + 1];
    __shared__ int   wo_s[CHUNK];
    __shared__ unsigned short csr_s[CSRCAP];
    __shared__ float red_s[512];

    const int g = blockIdx.x, s = blockIdx.y;
    const int tid = threadIdx.x, lane = tid & 63, w = tid >> 6;
    const int ebase = g * EPG, obase = g * NPER, nb = g * NCUR;
    const int d0 = s * CHUNK;
    const int d1 = (d0 + CHUNK < NCUR) ? d0 + CHUNK : NCUR;
    const int len = d1 - d0;

    for (int i = tid; i < NPER; i += 256) cmap_s[i] = cmap[obase + i];
    for (int i = tid; i < NCUR; i += 256) cnt_s[i] = 0;
    __syncthreads();

    for (int e = tid; e < EPG; e += 256) {
        int sl = cmap_s[src[ebase + e] - obase];
        int dl = cmap_s[dst[ebase + e] - obase];
        if ((sl | dl) >= 0) atomicAdd(&cnt_s[dl], 1);
    }
    __syncthreads();

    for (int i = tid; i < NCUR; i += 256)
        dinv_s[i] = rsqrtf((float)(cnt_s[i] + 1));

    if (tid < 64) {
        int v = (tid < len) ? cnt_s[d0 + tid] : 0;
        int x = v;
#pragma unroll
        for (int dlt = 1; dlt < 64; dlt <<= 1) {
            int y = __shfl_up(x, dlt);
            if (tid >= dlt) x += y;
        }
        int excl = x - v;
        if (tid < len) { rowptr_s[tid] = excl; wo_s[tid] = excl; }
        if (tid == 63) rowptr_s[len] = x;
    }
    __syncthreads();

    for (int e = tid; e < EPG; e += 256) {
        int sl = cmap_s[src[ebase + e] - obase];
        int dl = cmap_s[dst[ebase + e] - obase];
        if ((sl | dl) >= 0) {
            int r = dl - d0;
            if ((unsigned)r < (unsigned)len) {
                int pos = atomicAdd(&wo_s[r], 1);
                if (pos < CSRCAP) csr_s[pos] = (unsigned short)sl;
            }
        }
    }
    __syncthreads();

    const float2* x2 = (const float2*)xs;
    float2* o2p = (float2*)out;
    const float2 b2 = ((const float2*)bvec)[lane];
    float2 sum = make_float2(0.f, 0.f), sq = make_float2(0.f, 0.f);

    for (int d = d0 + w; d < d1; d += 4) {
        const int beg = rowptr_s[d - d0], end = rowptr_s[d - d0 + 1];
        const float dv = dinv_s[d];
        float2 xv = x2[(size_t)(nb + d) * 64 + lane];
        float2 acc = make_float2(dv * xv.x, dv * xv.y);
#pragma unroll 4
        for (int i = beg; i < end; ++i) {
            int sl = csr_s[i];
            float ws_ = dinv_s[sl];
            float2 v = x2[(size_t)(nb + sl) * 64 + lane];
            acc.x += ws_ * v.x; acc.y += ws_ * v.y;
        }
        float2 o = make_float2(b2.x + dv * acc.x, b2.y + dv * acc.y);
        o2p[(size_t)(nb + d) * 64 + lane] = o;
        sum.x += o.x; sum.y += o.y;
        sq.x  += o.x * o.x; sq.y += o.y * o.y;
    }

    float2* red2 = (float2*)red_s;
    red2[tid] = sum; __syncthreads();
    if (tid < 64) {
        float2 a = red2[tid], b_ = red2[tid + 64],
               c = red2[tid + 128], d_ = red2[tid + 192];
        atomicAdd(&bnpart[g * 256 + 2 * tid],     a.x + b_.x + c.x + d_.x);
        atomicAdd(&bnpart[g * 256 + 2 * tid + 1], a.y + b_.y + c.y + d_.y);
    }
    __syncthreads();
    red2[tid] = sq; __syncthreads();
    if (tid < 64) {
        float2 a = red2[tid], b_ = red2[tid + 64],
               c = red2[tid + 128], d_ = red2[tid + 192];
        atomicAdd(&bnpart[g * 256 + 128 + 2 * tid],     a.x + b_.x + c.x + d_.x);
        atomicAdd(&bnpart[g * 256 + 128 + 2 * tid + 1], a.y + b_.y + c.y + d_.y);
    }
}

// ---------------------------------------------------------------------------
// BN finalize (reduce per-graph partials) + att norm -> coefs[384]
// ---------------------------------------------------------------------------
__global__ void bnfin_kernel(const float* __restrict__ bnpart, float n,
                             const float* __restrict__ gamma,
                             const float* __restrict__ beta,
                             const float* __restrict__ att,
                             float* __restrict__ coefs)
{
    __shared__ float r[128];
    int t = threadIdx.x;
    float s = 0.f, q = 0.f;
#pragma unroll 4
    for (int g = 0; g < G; ++g) {
        s += bnpart[g * 256 + t];
        q += bnpart[g * 256 + 128 + t];
    }
    float av = att[t];
    r[t] = av * av;
    __syncthreads();
    for (int st = 64; st > 0; st >>= 1) {
        if (t < st) r[t] += r[t + st];
        __syncthreads();
    }
    float norm = sqrtf(r[0]);
    float mu   = s / n;
    float var  = q / n - mu * mu;
    float inv  = rsqrtf(var + 1e-5f);
    float a    = gamma[t] * inv;
    coefs[t]        = a;
    coefs[128 + t]  = beta[t] - mu * a;
    coefs[256 + t]  = av / norm;
}

// ---------------------------------------------------------------------------
// pool: 1024 threads (16 waves) per graph.
//   A: scores (wave per node)
//   B: pack keys (score, -idx) -> u64
//   C: O(N^2) rank selection (rank = new id; kept iff rank < KK) — replaces
//      bitonic sort: no syncs, no bank conflicts, exact JAX tie semantics.
//   D: gate + write newx + readout max/mean partials
//   E: cmap remap, zero bnpart slice
// ---------------------------------------------------------------------------
template<int NCUR, int KK>
__global__ __launch_bounds__(1024, 1) void pool_kernel(
    const float* __restrict__ gcn, const float* __restrict__ coefs,
    float* __restrict__ newx, short* __restrict__ cmap,
    float* __restrict__ sread, float* __restrict__ bnpart)
{
    __shared__ float score_s[NCUR];
    __shared__ unsigned long long key_s[NCUR];
    __shared__ short o2n_s[NCUR];
    __shared__ unsigned short n2o_s[KK];
    __shared__ float2 red2[1024];

    const int g = blockIdx.x, tid = threadIdx.x, lane = tid & 63, w = tid >> 6;
    const int nb = g * NCUR;
    const float a0 = coefs[lane],       a1 = coefs[64 + lane];
    const float c0 = coefs[128 + lane], c1 = coefs[192 + lane];
    const float t0 = coefs[256 + lane], t1 = coefs[320 + lane];

    // A: scores, one wave per node
    for (int i = w; i < NCUR; i += 16) {
        const float* row = gcn + (size_t)(nb + i) * 128;
        float h0 = fmaxf(a0 * row[lane] + c0, 0.f);
        float h1 = fmaxf(a1 * row[64 + lane] + c1, 0.f);
        float p  = h0 * t0 + h1 * t1;
#pragma unroll
        for (int off = 32; off > 0; off >>= 1) p += __shfl_down(p, off);
        if (lane == 0) score_s[i] = tanhf(p);
    }
    __syncthreads();

    // B: composite keys
    for (int i = tid; i < NCUR; i += 1024) {
        unsigned u   = __float_as_uint(score_s[i]);
        unsigned key = (u & 0x80000000u) ? ~u : (u | 0x80000000u);
        key_s[i] = ((unsigned long long)key << 32) |
                   (unsigned long long)(0xFFFFFFFFu - (unsigned)i);
    }
    __syncthreads();

    // C: rank selection (inner loop is wave-uniform LDS broadcast)
    for (int i = tid; i < NCUR; i += 1024) {
        const unsigned long long ki = key_s[i];
        int r = 0;
#pragma unroll 8
        for (int j = 0; j < NCUR; ++j) r += (key_s[j] > ki) ? 1 : 0;
        o2n_s[i] = (r < KK) ? (short)r : (short)-1;
        if (r < KK) n2o_s[r] = (unsigned short)i;
    }
    __syncthreads();

    // D: gating + newx + readout partials
    float mx0 = -1e30f, mx1 = -1e30f, sm0 = 0.f, sm1 = 0.f;
    for (int j2 = w; j2 < KK; j2 += 16) {
        int old = n2o_s[j2];
        float s = score_s[old];
        const float* row = gcn + (size_t)(nb + old) * 128;
        float h0 = fmaxf(a0 * row[lane] + c0, 0.f) * s;
        float h1 = fmaxf(a1 * row[64 + lane] + c1, 0.f) * s;
        float* orow = newx + (size_t)(g * KK + j2) * 128;
        orow[lane]      = h0;
        orow[64 + lane] = h1;
        mx0 = fmaxf(mx0, h0); mx1 = fmaxf(mx1, h1);
        sm0 += h0; sm1 += h1;
    }
    red2[tid] = make_float2(mx0, mx1);
    __syncthreads();
    if (tid < 64) {
        float m = -1e30f;
#pragma unroll
        for (int w2 = 0; w2 < 16; ++w2) m = fmaxf(m, red2[w2 * 64 + tid].x);
        sread[g * 256 + tid] += m;
    } else if (tid < 128) {
        int l = tid - 64;
        float m = -1e30f;
#pragma unroll
        for (int w2 = 0; w2 < 16; ++w2) m = fmaxf(m, red2[w2 * 64 + l].y);
        sread[g * 256 + tid] += m;
    }
    __syncthreads();
    red2[tid] = make_float2(sm0, sm1);
    __syncthreads();
    if (tid < 64) {
        float sm = 0.f;
#pragma unroll
        for (int w2 = 0; w2 < 16; ++w2) sm += red2[w2 * 64 + tid].x;
        sread[g * 256 + 128 + tid] += sm * (1.0f / KK);
    } else if (tid < 128) {
        int l = tid - 64;
        float sm = 0.f;
#pragma unroll
        for (int w2 = 0; w2 < 16; ++w2) sm += red2[w2 * 64 + l].y;
        sread[g * 256 + 128 + tid] += sm * (1.0f / KK);
    }

    // E: cmap remap + zero bnpart slice
    for (int o = tid; o < NPER; o += 1024) {
        int m = cmap[g * NPER + o];
        if (m >= 0) cmap[g * NPER + o] = o2n_s[m];
    }
    if (tid < 256) bnpart[g * 256 + tid] = 0.f;
}

// ---------------------------------------------------------------------------
// final MLP: out[g,2] = relu(s @ Wl1 + bl1) @ Wl2 + bl2
// ---------------------------------------------------------------------------
__global__ void final_kernel(const float* __restrict__ sread,
                             const float* __restrict__ Wl1,
                             const float* __restrict__ bl1,
                             const float* __restrict__ Wl2,
                             const float* __restrict__ bl2,
                             float* __restrict__ out)
{
    __shared__ float s_s[256];
    __shared__ float hid_s[128];
    int g = blockIdx.x, t = threadIdx.x;
    s_s[t]       = sread[g * 256 + t];
    s_s[128 + t] = sread[g * 256 + 128 + t];
    __syncthreads();
    float acc = bl1[t];
    for (int i = 0; i < 256; ++i) acc += s_s[i] * Wl1[i * 128 + t];
    hid_s[t] = fmaxf(acc, 0.f);
    __syncthreads();
    if (t < 2) {
        float o = bl2[t];
        for (int j = 0; j < 128; ++j) o += hid_s[j] * Wl2[j * 2 + t];
        out[g * 2 + t] = o;
    }
}

// ---------------------------------------------------------------------------
extern "C" void kernel_launch(void* const* d_in, const int* in_sizes, int n_in,
                              void* d_out, int out_size, void* d_ws, size_t ws_size,
                              hipStream_t stream)
{
    const float* x    = (const float*)d_in[0];
    const int*   ei   = (const int*)d_in[1];
    const float* Wp   = (const float*)d_in[3];
    const float* bp   = (const float*)d_in[4];
    const float* W1   = (const float*)d_in[5];
    const float* b1   = (const float*)d_in[6];
    const float* g1   = (const float*)d_in[7];
    const float* be1  = (const float*)d_in[8];
    const float* att1 = (const float*)d_in[9];
    const float* W2   = (const float*)d_in[10];
    const float* b2   = (const float*)d_in[11];
    const float* g2   = (const float*)d_in[12];
    const float* be2  = (const float*)d_in[13];
    const float* att2 = (const float*)d_in[14];
    const float* W3   = (const float*)d_in[15];
    const float* b3   = (const float*)d_in[16];
    const float* g3   = (const float*)d_in[17];
    const float* be3  = (const float*)d_in[18];
    const float* att3 = (const float*)d_in[19];
    const float* Wl1  = (const float*)d_in[20];
    const float* bl1  = (const float*)d_in[21];
    const float* Wl2  = (const float*)d_in[22];
    const float* bl2  = (const float*)d_in[23];
    float* out = (float*)d_out;

    const int* srcp = ei;
    const int* dstp = ei + E_TOT;

    char* ws = (char*)d_ws;
    float* bufA   = (float*)ws;                       // 33,554,432 B
    float* bufB   = (float*)(ws + 33554432);          // 33,554,432 B
    float* bnpart = (float*)(ws + 67108864);          //    131,072 B
    short* cmap   = (short*)(ws + 67239936);          //    131,072 B
    float* sread  = (float*)(ws + 67371008);          //    131,072 B
    float* coefs  = (float*)(ws + 67502080);          //      1,536 B

    init_kernel<<<256, 256, 0, stream>>>(cmap, sread, bnpart);

    // h0 = relu(x @ Wp + bp)
    gemm_kernel<INC, true><<<512, 256, 0, stream>>>(x, Wp, bp, bufA, NTOT);

    // ---- layer 1 ----
    gemm_kernel<128, false><<<512, 256, 0, stream>>>(bufA, W1, nullptr, bufB, NTOT);
    gather_kernel<512><<<dim3(G, 8), 256, 0, stream>>>(bufB, srcp, dstp, cmap, b1, bufA, bnpart);
    bnfin_kernel<<<1, 128, 0, stream>>>(bnpart, (float)NTOT, g1, be1, att1, coefs);
    pool_kernel<512, KP1><<<G, 1024, 0, stream>>>(bufA, coefs, bufB, cmap, sread, bnpart);

    // ---- layer 2 ----  (nodes: G*KP1 = 52480)
    gemm_kernel<128, false><<<410, 256, 0, stream>>>(bufB, W2, nullptr, bufA, G * KP1);
    gather_kernel<KP1><<<dim3(G, 8), 256, 0, stream>>>(bufA, srcp, dstp, cmap, b2, bufB, bnpart);
    bnfin_kernel<<<1, 128, 0, stream>>>(bnpart, (float)(G * KP1), g2, be2, att2, coefs);
    pool_kernel<KP1, KP2><<<G, 1024, 0, stream>>>(bufB, coefs, bufA, cmap, sread, bnpart);

    // ---- layer 3 ----  (nodes: G*KP2 = 41984)
    gemm_kernel<128, false><<<328, 256, 0, stream>>>(bufA, W3, nullptr, bufB, G * KP2);
    gather_kernel<KP2><<<dim3(G, 8), 256, 0, stream>>>(bufB, srcp, dstp, cmap, b3, bufA, bnpart);
    bnfin_kernel<<<1, 128, 0, stream>>>(bnpart, (float)(G * KP2), g3, be3, att3, coefs);
    pool_kernel<KP2, KP3><<<G, 1024, 0, stream>>>(bufA, coefs, bufB, cmap, sread, bnpart);

    final_kernel<<<G, 128, 0, stream>>>(sread, Wl1, bl1, Wl2, bl2, out);
}

// Round 5
// 590.824 us; speedup vs baseline: 4.2647x; 1.0533x over previous
//
#include <hip/hip_runtime.h>
#include <math.h>

#define G     128
#define NPER  512
#define NTOT  65536
#define E_TOT 1048576
#define EPG   8192
#define INC   100
#define HID   128
#define KP1   410
#define KP2   328
#define KP3   263

// ---------------------------------------------------------------------------
// init: identity cmap (short), zero sread + bnpart
// ---------------------------------------------------------------------------
__global__ void init_kernel(short* __restrict__ cmap, float* __restrict__ sread,
                            float* __restrict__ bnpart) {
    int t = blockIdx.x * 256 + threadIdx.x;
    if (t < NTOT) cmap[t] = (short)(t & (NPER - 1));
    if (t < G * 256) { sread[t] = 0.f; bnpart[t] = 0.f; }
}

// ---------------------------------------------------------------------------
// csr_build0: layer-1 CSR (identity mapping, all edges valid).
// One block per graph, 512 threads. count -> prefix -> scatter.
// ---------------------------------------------------------------------------
__global__ __launch_bounds__(512, 2) void csr_build0(
    const int* __restrict__ src, const int* __restrict__ dst,
    unsigned short* __restrict__ csr_g, int* __restrict__ rowptr_g)
{
    __shared__ int cnt_s[NPER];
    __shared__ int rowptr_s[NPER + 1];
    __shared__ int wo_s[NPER];
    __shared__ int chunksum_s[9];

    const int g = blockIdx.x, tid = threadIdx.x, lane = tid & 63, wv = tid >> 6;
    const int ebase = g * EPG, obase = g * NPER;

    cnt_s[tid] = 0;
    __syncthreads();
    for (int e = tid; e < EPG; e += 512)
        atomicAdd(&cnt_s[dst[ebase + e] - obase], 1);
    __syncthreads();

    int v = cnt_s[tid], x = v;
#pragma unroll
    for (int d = 1; d < 64; d <<= 1) {
        int y = __shfl_up(x, d);
        if (lane >= d) x += y;
    }
    if (lane == 63) chunksum_s[wv] = x;
    __syncthreads();
    if (tid == 0) {
        int acc = 0;
#pragma unroll
        for (int k = 0; k < 8; ++k) { int t = chunksum_s[k]; chunksum_s[k] = acc; acc += t; }
    }
    __syncthreads();
    int excl = x - v + chunksum_s[wv];
    rowptr_s[tid] = excl; wo_s[tid] = excl;
    if (tid == 511) rowptr_s[512] = excl + v;
    __syncthreads();

    for (int i = tid; i <= NPER; i += 512) rowptr_g[g * 513 + i] = rowptr_s[i];
    for (int e = tid; e < EPG; e += 512) {
        int sl = src[ebase + e] - obase, dl = dst[ebase + e] - obase;
        int pos = atomicAdd(&wo_s[dl], 1);
        csr_g[g * EPG + pos] = (unsigned short)sl;
    }
}

// ---------------------------------------------------------------------------
// GEMM: out[M x 128] = A[M x K] @ W[K x 128]  (+bias, relu if RELU)
// ---------------------------------------------------------------------------
template<int K, bool RELU>
__global__ __launch_bounds__(256, 1) void gemm_kernel(
    const float* __restrict__ A, const float* __restrict__ W,
    const float* __restrict__ bias, float* __restrict__ out, int M)
{
    __shared__ float Ws[K * 128];
    __shared__ float As[128 * (K + 1)];
    const int tid  = threadIdx.x;
    const int row0 = blockIdx.x * 128;

    for (int i = tid; i < K * 32; i += 256)
        ((float4*)Ws)[i] = ((const float4*)W)[i];

    const float4* A4 = (const float4*)(A + (size_t)row0 * K);
    for (int i = tid; i < K * 32; i += 256) {
        float4 v = A4[i];
        int p = i * 4;
        int r = p / K, k = p - r * K;           As[r * (K + 1) + k] = v.x;
        p++;  r = p / K; k = p - r * K;          As[r * (K + 1) + k] = v.y;
        p++;  r = p / K; k = p - r * K;          As[r * (K + 1) + k] = v.z;
        p++;  r = p / K; k = p - r * K;          As[r * (K + 1) + k] = v.w;
    }
    __syncthreads();

    const int r0 = (tid >> 4) * 8;
    const int c0 = (tid & 15) * 8;
    float acc[8][8];
#pragma unroll
    for (int i = 0; i < 8; ++i)
#pragma unroll
        for (int j = 0; j < 8; ++j) acc[i][j] = 0.f;

    for (int k = 0; k < K; ++k) {
        float4 b0 = *(const float4*)&Ws[k * 128 + c0];
        float4 b1 = *(const float4*)&Ws[k * 128 + c0 + 4];
        float a[8];
#pragma unroll
        for (int i = 0; i < 8; ++i) a[i] = As[(r0 + i) * (K + 1) + k];
#pragma unroll
        for (int i = 0; i < 8; ++i) {
            acc[i][0] += a[i] * b0.x;  acc[i][1] += a[i] * b0.y;
            acc[i][2] += a[i] * b0.z;  acc[i][3] += a[i] * b0.w;
            acc[i][4] += a[i] * b1.x;  acc[i][5] += a[i] * b1.y;
            acc[i][6] += a[i] * b1.z;  acc[i][7] += a[i] * b1.w;
        }
    }

#pragma unroll
    for (int i = 0; i < 8; ++i) {
        int row = row0 + r0 + i;
        float o[8];
#pragma unroll
        for (int j = 0; j < 8; ++j) {
            float v = acc[i][j];
            if (RELU) v = fmaxf(v + bias[c0 + j], 0.f);
            o[j] = v;
        }
        float* po = out + (size_t)row * 128 + c0;
        *(float4*)po       = make_float4(o[0], o[1], o[2], o[3]);
        *(float4*)(po + 4) = make_float4(o[4], o[5], o[6], o[7]);
    }
}

// ---------------------------------------------------------------------------
// gather: pure compute now. grid (G,8), 256 threads.
//   loads rowptr (full graph), derives dinv = rsqrt(deg+1) from rowptr diffs,
//   stages its chunk's CSR slice, then wave-per-dst register accumulation.
// ---------------------------------------------------------------------------
template<int NCUR>
__global__ __launch_bounds__(256, 4) void gather_kernel(
    const float* __restrict__ xs, const unsigned short* __restrict__ csr_g,
    const int* __restrict__ rowptr_g, const float* __restrict__ bvec,
    float* __restrict__ out, float* __restrict__ bnpart)
{
    constexpr int CHUNK = (NCUR + 7) / 8;
    constexpr int CSRCAP = 2560;
    __shared__ int   rowptr_s[NCUR + 1];
    __shared__ float dinv_s[NCUR];
    __shared__ unsigned short csr_s[CSRCAP];
    __shared__ float red_s[512];

    const int g = blockIdx.x, s = blockIdx.y;
    const int tid = threadIdx.x, lane = tid & 63, w = tid >> 6;
    const int nb = g * NCUR;
    const int d0 = s * CHUNK;
    const int d1 = (d0 + CHUNK < NCUR) ? d0 + CHUNK : NCUR;

    const int* rp = rowptr_g + g * 513;
    for (int i = tid; i <= NCUR; i += 256) rowptr_s[i] = rp[i];
    __syncthreads();
    for (int i = tid; i < NCUR; i += 256)
        dinv_s[i] = rsqrtf((float)(rowptr_s[i + 1] - rowptr_s[i] + 1));

    const int base = rowptr_s[d0];
    int nume = rowptr_s[d1] - base;
    if (nume > CSRCAP) nume = CSRCAP;
    const unsigned short* cg = csr_g + g * EPG + base;
    for (int i = tid; i < nume; i += 256) csr_s[i] = cg[i];
    __syncthreads();

    const float2* x2 = (const float2*)xs;
    float2* o2p = (float2*)out;
    const float2 b2 = ((const float2*)bvec)[lane];
    float2 sum = make_float2(0.f, 0.f), sq = make_float2(0.f, 0.f);

    for (int d = d0 + w; d < d1; d += 4) {
        const int beg = rowptr_s[d] - base, end = rowptr_s[d + 1] - base;
        const float dv = dinv_s[d];
        float2 xv = x2[(size_t)(nb + d) * 64 + lane];
        float2 acc = make_float2(dv * xv.x, dv * xv.y);
#pragma unroll 4
        for (int i = beg; i < end; ++i) {
            int sl = csr_s[i];                    // wave-uniform broadcast
            float ws_ = dinv_s[sl];               // wave-uniform broadcast
            float2 v = x2[(size_t)(nb + sl) * 64 + lane];
            acc.x += ws_ * v.x; acc.y += ws_ * v.y;
        }
        float2 o = make_float2(b2.x + dv * acc.x, b2.y + dv * acc.y);
        o2p[(size_t)(nb + d) * 64 + lane] = o;
        sum.x += o.x; sum.y += o.y;
        sq.x  += o.x * o.x; sq.y += o.y * o.y;
    }

    float2* red2 = (float2*)red_s;
    red2[tid] = sum; __syncthreads();
    if (tid < 64) {
        float2 a = red2[tid], b_ = red2[tid + 64],
               c = red2[tid + 128], d_ = red2[tid + 192];
        atomicAdd(&bnpart[g * 256 + 2 * tid],     a.x + b_.x + c.x + d_.x);
        atomicAdd(&bnpart[g * 256 + 2 * tid + 1], a.y + b_.y + c.y + d_.y);
    }
    __syncthreads();
    red2[tid] = sq; __syncthreads();
    if (tid < 64) {
        float2 a = red2[tid], b_ = red2[tid + 64],
               c = red2[tid + 128], d_ = red2[tid + 192];
        atomicAdd(&bnpart[g * 256 + 128 + 2 * tid],     a.x + b_.x + c.x + d_.x);
        atomicAdd(&bnpart[g * 256 + 128 + 2 * tid + 1], a.y + b_.y + c.y + d_.y);
    }
}

// ---------------------------------------------------------------------------
// BN finalize + att norm -> coefs[384]
// ---------------------------------------------------------------------------
__global__ void bnfin_kernel(const float* __restrict__ bnpart, float n,
                             const float* __restrict__ gamma,
                             const float* __restrict__ beta,
                             const float* __restrict__ att,
                             float* __restrict__ coefs)
{
    __shared__ float r[128];
    int t = threadIdx.x;
    float s = 0.f, q = 0.f;
#pragma unroll 4
    for (int g = 0; g < G; ++g) {
        s += bnpart[g * 256 + t];
        q += bnpart[g * 256 + 128 + t];
    }
    float av = att[t];
    r[t] = av * av;
    __syncthreads();
    for (int st = 64; st > 0; st >>= 1) {
        if (t < st) r[t] += r[t + st];
        __syncthreads();
    }
    float norm = sqrtf(r[0]);
    float mu   = s / n;
    float var  = q / n - mu * mu;
    float inv  = rsqrtf(var + 1e-5f);
    float a    = gamma[t] * inv;
    coefs[t]        = a;
    coefs[128 + t]  = beta[t] - mu * a;
    coefs[256 + t]  = av / norm;
}

// ---------------------------------------------------------------------------
// pool: 1024 threads per graph. scores -> rank-select -> gate/readout ->
// cmap remap; if BUILD: construct next layer's CSR+rowptr (single edge scan).
// ---------------------------------------------------------------------------
template<int NCUR, int KK, bool BUILD>
__global__ __launch_bounds__(1024, 1) void pool_kernel(
    const float* __restrict__ gcn, const float* __restrict__ coefs,
    float* __restrict__ newx, short* __restrict__ cmap,
    float* __restrict__ sread, float* __restrict__ bnpart,
    const int* __restrict__ src, const int* __restrict__ dst,
    unsigned short* __restrict__ csr_g, int* __restrict__ rowptr_g)
{
    __shared__ float score_s[NCUR];
    __shared__ unsigned long long key_s[NCUR];
    __shared__ short o2n_s[NCUR];
    __shared__ unsigned short n2o_s[KK];
    __shared__ short cmap_s[NPER];
    __shared__ float2 red2[1024];
    __shared__ int   cnt_s[512];
    __shared__ int   rowptr_s[513];
    __shared__ int   wo_s[512];
    __shared__ int   chunksum_s[9];

    const int g = blockIdx.x, tid = threadIdx.x, lane = tid & 63, w = tid >> 6;
    const int nb = g * NCUR;
    const int ebase = g * EPG, obase = g * NPER;
    const float a0 = coefs[lane],       a1 = coefs[64 + lane];
    const float c0 = coefs[128 + lane], c1 = coefs[192 + lane];
    const float t0 = coefs[256 + lane], t1 = coefs[320 + lane];

    // phase 0: load cmap
    for (int i = tid; i < NPER; i += 1024) cmap_s[i] = cmap[obase + i];

    // A: scores, one wave per node
    for (int i = w; i < NCUR; i += 16) {
        const float* row = gcn + (size_t)(nb + i) * 128;
        float h0 = fmaxf(a0 * row[lane] + c0, 0.f);
        float h1 = fmaxf(a1 * row[64 + lane] + c1, 0.f);
        float p  = h0 * t0 + h1 * t1;
#pragma unroll
        for (int off = 32; off > 0; off >>= 1) p += __shfl_down(p, off);
        if (lane == 0) score_s[i] = tanhf(p);
    }
    __syncthreads();

    // B: composite keys
    for (int i = tid; i < NCUR; i += 1024) {
        unsigned u   = __float_as_uint(score_s[i]);
        unsigned key = (u & 0x80000000u) ? ~u : (u | 0x80000000u);
        key_s[i] = ((unsigned long long)key << 32) |
                   (unsigned long long)(0xFFFFFFFFu - (unsigned)i);
    }
    __syncthreads();

    // C: rank selection
    for (int i = tid; i < NCUR; i += 1024) {
        const unsigned long long ki = key_s[i];
        int r = 0;
#pragma unroll 8
        for (int j = 0; j < NCUR; ++j) r += (key_s[j] > ki) ? 1 : 0;
        o2n_s[i] = (r < KK) ? (short)r : (short)-1;
        if (r < KK) n2o_s[r] = (unsigned short)i;
    }
    __syncthreads();

    // D: gating + newx + readout partials
    float mx0 = -1e30f, mx1 = -1e30f, sm0 = 0.f, sm1 = 0.f;
    for (int j2 = w; j2 < KK; j2 += 16) {
        int old = n2o_s[j2];
        float s = score_s[old];
        const float* row = gcn + (size_t)(nb + old) * 128;
        float h0 = fmaxf(a0 * row[lane] + c0, 0.f) * s;
        float h1 = fmaxf(a1 * row[64 + lane] + c1, 0.f) * s;
        float* orow = newx + (size_t)(g * KK + j2) * 128;
        orow[lane]      = h0;
        orow[64 + lane] = h1;
        mx0 = fmaxf(mx0, h0); mx1 = fmaxf(mx1, h1);
        sm0 += h0; sm1 += h1;
    }
    red2[tid] = make_float2(mx0, mx1);
    __syncthreads();
    if (tid < 64) {
        float m = -1e30f;
#pragma unroll
        for (int w2 = 0; w2 < 16; ++w2) m = fmaxf(m, red2[w2 * 64 + tid].x);
        sread[g * 256 + tid] += m;
    } else if (tid < 128) {
        int l = tid - 64;
        float m = -1e30f;
#pragma unroll
        for (int w2 = 0; w2 < 16; ++w2) m = fmaxf(m, red2[w2 * 64 + l].y);
        sread[g * 256 + tid] += m;
    }
    __syncthreads();
    red2[tid] = make_float2(sm0, sm1);
    __syncthreads();
    if (tid < 64) {
        float sm = 0.f;
#pragma unroll
        for (int w2 = 0; w2 < 16; ++w2) sm += red2[w2 * 64 + tid].x;
        sread[g * 256 + 128 + tid] += sm * (1.0f / KK);
    } else if (tid < 128) {
        int l = tid - 64;
        float sm = 0.f;
#pragma unroll
        for (int w2 = 0; w2 < 16; ++w2) sm += red2[w2 * 64 + l].y;
        sread[g * 256 + 128 + tid] += sm * (1.0f / KK);
    }

    // E: cmap remap (LDS + global), zero bnpart slice
    for (int o = tid; o < NPER; o += 1024) {
        int m = cmap_s[o];
        short nm = (m >= 0) ? o2n_s[m] : (short)-1;
        cmap_s[o] = nm;
        cmap[obase + o] = nm;
    }
    if (tid < 256) bnpart[g * 256 + tid] = 0.f;

    if (!BUILD) return;
    __syncthreads();

    // F: build next layer's CSR (dst ids in [0,KK))
    if (tid < 512) cnt_s[tid] = 0;
    __syncthreads();
    for (int e = tid; e < EPG; e += 1024) {
        int sl = cmap_s[src[ebase + e] - obase];
        int dl = cmap_s[dst[ebase + e] - obase];
        if ((sl | dl) >= 0) atomicAdd(&cnt_s[dl], 1);
    }
    __syncthreads();
    int v = 0, x = 0;
    if (tid < 512) {
        v = cnt_s[tid]; x = v;
#pragma unroll
        for (int d = 1; d < 64; d <<= 1) {
            int y = __shfl_up(x, d);
            if (lane >= d) x += y;
        }
        if (lane == 63) chunksum_s[w] = x;
    }
    __syncthreads();
    if (tid == 0) {
        int acc = 0;
#pragma unroll
        for (int k = 0; k < 8; ++k) { int t = chunksum_s[k]; chunksum_s[k] = acc; acc += t; }
    }
    __syncthreads();
    if (tid < 512) {
        int excl = x - v + chunksum_s[w];
        rowptr_s[tid] = excl; wo_s[tid] = excl;
        if (tid == 511) rowptr_s[512] = excl + v;
    }
    __syncthreads();
    for (int i = tid; i <= 512; i += 1024) rowptr_g[g * 513 + i] = rowptr_s[i];
    for (int e = tid; e < EPG; e += 1024) {
        int sl = cmap_s[src[ebase + e] - obase];
        int dl = cmap_s[dst[ebase + e] - obase];
        if ((sl | dl) >= 0) {
            int pos = atomicAdd(&wo_s[dl], 1);
            csr_g[g * EPG + pos] = (unsigned short)sl;
        }
    }
}

// ---------------------------------------------------------------------------
// final MLP
// ---------------------------------------------------------------------------
__global__ void final_kernel(const float* __restrict__ sread,
                             const float* __restrict__ Wl1,
                             const float* __restrict__ bl1,
                             const float* __restrict__ Wl2,
                             const float* __restrict__ bl2,
                             float* __restrict__ out)
{
    __shared__ float s_s[256];
    __shared__ float hid_s[128];
    int g = blockIdx.x, t = threadIdx.x;
    s_s[t]       = sread[g * 256 + t];
    s_s[128 + t] = sread[g * 256 + 128 + t];
    __syncthreads();
    float acc = bl1[t];
    for (int i = 0; i < 256; ++i) acc += s_s[i] * Wl1[i * 128 + t];
    hid_s[t] = fmaxf(acc, 0.f);
    __syncthreads();
    if (t < 2) {
        float o = bl2[t];
        for (int j = 0; j < 128; ++j) o += hid_s[j] * Wl2[j * 2 + t];
        out[g * 2 + t] = o;
    }
}

// ---------------------------------------------------------------------------
extern "C" void kernel_launch(void* const* d_in, const int* in_sizes, int n_in,
                              void* d_out, int out_size, void* d_ws, size_t ws_size,
                              hipStream_t stream)
{
    const float* x    = (const float*)d_in[0];
    const int*   ei   = (const int*)d_in[1];
    const float* Wp   = (const float*)d_in[3];
    const float* bp   = (const float*)d_in[4];
    const float* W1   = (const float*)d_in[5];
    const float* b1   = (const float*)d_in[6];
    const float* g1   = (const float*)d_in[7];
    const float* be1  = (const float*)d_in[8];
    const float* att1 = (const float*)d_in[9];
    const float* W2   = (const float*)d_in[10];
    const float* b2   = (const float*)d_in[11];
    const float* g2   = (const float*)d_in[12];
    const float* be2  = (const float*)d_in[13];
    const float* att2 = (const float*)d_in[14];
    const float* W3   = (const float*)d_in[15];
    const float* b3   = (const float*)d_in[16];
    const float* g3   = (const float*)d_in[17];
    const float* be3  = (const float*)d_in[18];
    const float* att3 = (const float*)d_in[19];
    const float* Wl1  = (const float*)d_in[20];
    const float* bl1  = (const float*)d_in[21];
    const float* Wl2  = (const float*)d_in[22];
    const float* bl2  = (const float*)d_in[23];
    float* out = (float*)d_out;

    const int* srcp = ei;
    const int* dstp = ei + E_TOT;

    char* ws = (char*)d_ws;
    float*          bufA   = (float*)ws;                      // 33,554,432 B
    float*          bufB   = (float*)(ws + 33554432);         // 33,554,432 B
    unsigned short* csr    = (unsigned short*)(ws + 67108864);//  2,097,152 B
    int*            rowptr = (int*)  (ws + 69206016);         //    262,656 B
    float*          bnpart = (float*)(ws + 69468672);         //    131,072 B
    short*          cmap   = (short*)(ws + 69599744);         //    131,072 B
    float*          sread  = (float*)(ws + 69730816);         //    131,072 B
    float*          coefs  = (float*)(ws + 69861888);         //      1,536 B

    init_kernel<<<256, 256, 0, stream>>>(cmap, sread, bnpart);
    csr_build0<<<G, 512, 0, stream>>>(srcp, dstp, csr, rowptr);

    // h0 = relu(x @ Wp + bp)
    gemm_kernel<INC, true><<<512, 256, 0, stream>>>(x, Wp, bp, bufA, NTOT);

    // ---- layer 1 ----
    gemm_kernel<128, false><<<512, 256, 0, stream>>>(bufA, W1, nullptr, bufB, NTOT);
    gather_kernel<512><<<dim3(G, 8), 256, 0, stream>>>(bufB, csr, rowptr, b1, bufA, bnpart);
    bnfin_kernel<<<1, 128, 0, stream>>>(bnpart, (float)NTOT, g1, be1, att1, coefs);
    pool_kernel<512, KP1, true><<<G, 1024, 0, stream>>>(bufA, coefs, bufB, cmap, sread, bnpart,
                                                        srcp, dstp, csr, rowptr);

    // ---- layer 2 ----  (nodes: G*KP1 = 52480)
    gemm_kernel<128, false><<<410, 256, 0, stream>>>(bufB, W2, nullptr, bufA, G * KP1);
    gather_kernel<KP1><<<dim3(G, 8), 256, 0, stream>>>(bufA, csr, rowptr, b2, bufB, bnpart);
    bnfin_kernel<<<1, 128, 0, stream>>>(bnpart, (float)(G * KP1), g2, be2, att2, coefs);
    pool_kernel<KP1, KP2, true><<<G, 1024, 0, stream>>>(bufB, coefs, bufA, cmap, sread, bnpart,
                                                        srcp, dstp, csr, rowptr);

    // ---- layer 3 ----  (nodes: G*KP2 = 41984)
    gemm_kernel<128, false><<<328, 256, 0, stream>>>(bufA, W3, nullptr, bufB, G * KP2);
    gather_kernel<KP2><<<dim3(G, 8), 256, 0, stream>>>(bufB, csr, rowptr, b3, bufA, bnpart);
    bnfin_kernel<<<1, 128, 0, stream>>>(bnpart, (float)(G * KP2), g3, be3, att3, coefs);
    pool_kernel<KP2, KP3, false><<<G, 1024, 0, stream>>>(bufA, coefs, bufB, cmap, sread, bnpart,
                                                         srcp, dstp, csr, rowptr);

    final_kernel<<<G, 128, 0, stream>>>(sread, Wl1, bl1, Wl2, bl2, out);
}

// Round 6
// 509.242 us; speedup vs baseline: 4.9479x; 1.1602x over previous
//
#include <hip/hip_runtime.h>
#include <math.h>

#define G     128
#define NPER  512
#define NTOT  65536
#define E_TOT 1048576
#define EPG   8192
#define INC   100
#define HID   128
#define KP1   410
#define KP2   328
#define KP3   263

// ---------------------------------------------------------------------------
// init: identity cmap (short), zero sread + bnpart
// ---------------------------------------------------------------------------
__global__ void init_kernel(short* __restrict__ cmap, float* __restrict__ sread,
                            float* __restrict__ bnpart) {
    int t = blockIdx.x * 256 + threadIdx.x;
    if (t < NTOT) cmap[t] = (short)(t & (NPER - 1));
    if (t < G * 256) { sread[t] = 0.f; bnpart[t] = 0.f; }
}

// ---------------------------------------------------------------------------
// csr_build0: layer-1 CSR (identity mapping, all edges valid).
// ---------------------------------------------------------------------------
__global__ __launch_bounds__(512, 2) void csr_build0(
    const int* __restrict__ src, const int* __restrict__ dst,
    unsigned short* __restrict__ csr_g, int* __restrict__ rowptr_g)
{
    __shared__ int cnt_s[NPER];
    __shared__ int rowptr_s[NPER + 1];
    __shared__ int wo_s[NPER];
    __shared__ int chunksum_s[9];

    const int g = blockIdx.x, tid = threadIdx.x, lane = tid & 63, wv = tid >> 6;
    const int ebase = g * EPG, obase = g * NPER;

    cnt_s[tid] = 0;
    __syncthreads();
    for (int e = tid; e < EPG; e += 512)
        atomicAdd(&cnt_s[dst[ebase + e] - obase], 1);
    __syncthreads();

    int v = cnt_s[tid], x = v;
#pragma unroll
    for (int d = 1; d < 64; d <<= 1) {
        int y = __shfl_up(x, d);
        if (lane >= d) x += y;
    }
    if (lane == 63) chunksum_s[wv] = x;
    __syncthreads();
    if (tid == 0) {
        int acc = 0;
#pragma unroll
        for (int k = 0; k < 8; ++k) { int t = chunksum_s[k]; chunksum_s[k] = acc; acc += t; }
    }
    __syncthreads();
    int excl = x - v + chunksum_s[wv];
    rowptr_s[tid] = excl; wo_s[tid] = excl;
    if (tid == 511) rowptr_s[512] = excl + v;
    __syncthreads();

    for (int i = tid; i <= NPER; i += 512) rowptr_g[g * 513 + i] = rowptr_s[i];
    for (int e = tid; e < EPG; e += 512) {
        int sl = src[ebase + e] - obase, dl = dst[ebase + e] - obase;
        int pos = atomicAdd(&wo_s[dl], 1);
        csr_g[g * EPG + pos] = (unsigned short)sl;
    }
}

// ---------------------------------------------------------------------------
// GEMM: out[M x 128] = A[M x K] @ W[K x 128]  (+bias, relu if RELU)
// 256 thr, tile 128x128, thread 8x8, K-chunked (KC=32) LDS staging:
//   Ws [32][128] row-major, As [32][132] TRANSPOSED (aligned float4 reads,
//   banks r0%32 = {0,8,16,24}+4kk -> conflict-free). ~33 KB LDS -> 2+ blk/CU.
// ---------------------------------------------------------------------------
template<int K, bool RELU>
__global__ __launch_bounds__(256, 2) void gemm_kernel(
    const float* __restrict__ A, const float* __restrict__ W,
    const float* __restrict__ bias, float* __restrict__ out, int M)
{
    constexpr int KC = 32;
    __shared__ float Ws[KC][128];
    __shared__ float As[KC][132];
    const int tid  = threadIdx.x;
    const int row0 = blockIdx.x * 128;
    const int r0 = (tid >> 4) * 8;
    const int c0 = (tid & 15) * 8;

    float acc[8][8];
#pragma unroll
    for (int i = 0; i < 8; ++i)
#pragma unroll
        for (int j = 0; j < 8; ++j) acc[i][j] = 0.f;

    for (int k0 = 0; k0 < K; k0 += KC) {
        const int kc  = (K - k0 < KC) ? (K - k0) : KC;
        const int nf4 = kc >> 2;                 // float4s per A-row chunk

        // stage W chunk [kc][128] (coalesced float4)
        for (int i = tid; i < kc * 32; i += 256) {
            int kk = i >> 5, c4 = i & 31;
            *((float4*)&Ws[kk][0] + c4) =
                *((const float4*)(W + (size_t)(k0 + kk) * 128) + c4);
        }
        // stage A chunk transposed: As[kk][row] = A[row0+row][k0+kk]
        for (int i = tid; i < nf4 * 128; i += 256) {
            int row = i / nf4, f4 = i - row * nf4;
            float4 v = *(const float4*)(A + (size_t)(row0 + row) * K + k0 + f4 * 4);
            As[f4 * 4 + 0][row] = v.x;
            As[f4 * 4 + 1][row] = v.y;
            As[f4 * 4 + 2][row] = v.z;
            As[f4 * 4 + 3][row] = v.w;
        }
        __syncthreads();

        for (int kk = 0; kk < kc; ++kk) {
            float4 b0 = *(const float4*)&Ws[kk][c0];
            float4 b1 = *(const float4*)&Ws[kk][c0 + 4];
            float4 a0 = *(const float4*)&As[kk][r0];
            float4 a1 = *(const float4*)&As[kk][r0 + 4];
            float a[8] = {a0.x, a0.y, a0.z, a0.w, a1.x, a1.y, a1.z, a1.w};
            float b[8] = {b0.x, b0.y, b0.z, b0.w, b1.x, b1.y, b1.z, b1.w};
#pragma unroll
            for (int i = 0; i < 8; ++i)
#pragma unroll
                for (int j = 0; j < 8; ++j)
                    acc[i][j] += a[i] * b[j];
        }
        __syncthreads();
    }

#pragma unroll
    for (int i = 0; i < 8; ++i) {
        int row = row0 + r0 + i;
        float o[8];
#pragma unroll
        for (int j = 0; j < 8; ++j) {
            float v = acc[i][j];
            if (RELU) v = fmaxf(v + bias[c0 + j], 0.f);
            o[j] = v;
        }
        float* po = out + (size_t)row * 128 + c0;
        *(float4*)po       = make_float4(o[0], o[1], o[2], o[3]);
        *(float4*)(po + 4) = make_float4(o[4], o[5], o[6], o[7]);
    }
}

// ---------------------------------------------------------------------------
// gather: pure compute. grid (G,8), 256 threads.
// ---------------------------------------------------------------------------
template<int NCUR>
__global__ __launch_bounds__(256, 4) void gather_kernel(
    const float* __restrict__ xs, const unsigned short* __restrict__ csr_g,
    const int* __restrict__ rowptr_g, const float* __restrict__ bvec,
    float* __restrict__ out, float* __restrict__ bnpart)
{
    constexpr int CHUNK = (NCUR + 7) / 8;
    constexpr int CSRCAP = 2560;
    __shared__ int   rowptr_s[NCUR + 1];
    __shared__ float dinv_s[NCUR];
    __shared__ unsigned short csr_s[CSRCAP];
    __shared__ float red_s[512];

    const int g = blockIdx.x, s = blockIdx.y;
    const int tid = threadIdx.x, lane = tid & 63, w = tid >> 6;
    const int nb = g * NCUR;
    const int d0 = s * CHUNK;
    const int d1 = (d0 + CHUNK < NCUR) ? d0 + CHUNK : NCUR;

    const int* rp = rowptr_g + g * 513;
    for (int i = tid; i <= NCUR; i += 256) rowptr_s[i] = rp[i];
    __syncthreads();
    for (int i = tid; i < NCUR; i += 256)
        dinv_s[i] = rsqrtf((float)(rowptr_s[i + 1] - rowptr_s[i] + 1));

    const int base = rowptr_s[d0];
    int nume = rowptr_s[d1] - base;
    if (nume > CSRCAP) nume = CSRCAP;
    const unsigned short* cg = csr_g + g * EPG + base;
    for (int i = tid; i < nume; i += 256) csr_s[i] = cg[i];
    __syncthreads();

    const float2* x2 = (const float2*)xs;
    float2* o2p = (float2*)out;
    const float2 b2 = ((const float2*)bvec)[lane];
    float2 sum = make_float2(0.f, 0.f), sq = make_float2(0.f, 0.f);

    for (int d = d0 + w; d < d1; d += 4) {
        const int beg = rowptr_s[d] - base, end = rowptr_s[d + 1] - base;
        const float dv = dinv_s[d];
        float2 xv = x2[(size_t)(nb + d) * 64 + lane];
        float2 acc = make_float2(dv * xv.x, dv * xv.y);
#pragma unroll 4
        for (int i = beg; i < end; ++i) {
            int sl = csr_s[i];
            float ws_ = dinv_s[sl];
            float2 v = x2[(size_t)(nb + sl) * 64 + lane];
            acc.x += ws_ * v.x; acc.y += ws_ * v.y;
        }
        float2 o = make_float2(b2.x + dv * acc.x, b2.y + dv * acc.y);
        o2p[(size_t)(nb + d) * 64 + lane] = o;
        sum.x += o.x; sum.y += o.y;
        sq.x  += o.x * o.x; sq.y += o.y * o.y;
    }

    float2* red2 = (float2*)red_s;
    red2[tid] = sum; __syncthreads();
    if (tid < 64) {
        float2 a = red2[tid], b_ = red2[tid + 64],
               c = red2[tid + 128], d_ = red2[tid + 192];
        atomicAdd(&bnpart[g * 256 + 2 * tid],     a.x + b_.x + c.x + d_.x);
        atomicAdd(&bnpart[g * 256 + 2 * tid + 1], a.y + b_.y + c.y + d_.y);
    }
    __syncthreads();
    red2[tid] = sq; __syncthreads();
    if (tid < 64) {
        float2 a = red2[tid], b_ = red2[tid + 64],
               c = red2[tid + 128], d_ = red2[tid + 192];
        atomicAdd(&bnpart[g * 256 + 128 + 2 * tid],     a.x + b_.x + c.x + d_.x);
        atomicAdd(&bnpart[g * 256 + 128 + 2 * tid + 1], a.y + b_.y + c.y + d_.y);
    }
}

// ---------------------------------------------------------------------------
// BN finalize + att norm -> coefs[384].  1024 threads: 8 graph-slices in
// parallel (the old 128-thread version serialized 128 dependent loads).
// ---------------------------------------------------------------------------
__global__ __launch_bounds__(1024, 1) void bnfin_kernel(
    const float* __restrict__ bnpart, float n,
    const float* __restrict__ gamma, const float* __restrict__ beta,
    const float* __restrict__ att, float* __restrict__ coefs)
{
    __shared__ float ssum[8][128];
    __shared__ float ssq[8][128];
    __shared__ float r[128];
    const int t = threadIdx.x & 127, slice = threadIdx.x >> 7;
    float s = 0.f, q = 0.f;
    for (int g = slice; g < G; g += 8) {
        s += bnpart[g * 256 + t];
        q += bnpart[g * 256 + 128 + t];
    }
    ssum[slice][t] = s; ssq[slice][t] = q;
    if (threadIdx.x < 128) { float av = att[t]; r[t] = av * av; }
    __syncthreads();
    if (threadIdx.x < 128) {
        float S = 0.f, Q = 0.f;
#pragma unroll
        for (int k = 0; k < 8; ++k) { S += ssum[k][t]; Q += ssq[k][t]; }
        // att-norm reduction over r[0..127] (single wave-pair via LDS tree)
        for (int st = 64; st > 0; st >>= 1) {
            if (t < st) r[t] += r[t + st];
            __syncthreads();
        }
        float norm = sqrtf(r[0]);
        float mu   = S / n;
        float var  = Q / n - mu * mu;
        float inv  = rsqrtf(var + 1e-5f);
        float a    = gamma[t] * inv;
        coefs[t]        = a;
        coefs[128 + t]  = beta[t] - mu * a;
        coefs[256 + t]  = att[t] / norm;
    }
}

// ---------------------------------------------------------------------------
// pool: 1024 threads per graph. scores -> rank-select -> gate/readout ->
// cmap remap; if BUILD: construct next layer's CSR+rowptr.
// ---------------------------------------------------------------------------
template<int NCUR, int KK, bool BUILD>
__global__ __launch_bounds__(1024, 1) void pool_kernel(
    const float* __restrict__ gcn, const float* __restrict__ coefs,
    float* __restrict__ newx, short* __restrict__ cmap,
    float* __restrict__ sread, float* __restrict__ bnpart,
    const int* __restrict__ src, const int* __restrict__ dst,
    unsigned short* __restrict__ csr_g, int* __restrict__ rowptr_g)
{
    __shared__ float score_s[NCUR];
    __shared__ unsigned long long key_s[NCUR];
    __shared__ short o2n_s[NCUR];
    __shared__ unsigned short n2o_s[KK];
    __shared__ short cmap_s[NPER];
    __shared__ float2 red2[1024];
    __shared__ int   cnt_s[512];
    __shared__ int   rowptr_s[513];
    __shared__ int   wo_s[512];
    __shared__ int   chunksum_s[9];

    const int g = blockIdx.x, tid = threadIdx.x, lane = tid & 63, w = tid >> 6;
    const int nb = g * NCUR;
    const int ebase = g * EPG, obase = g * NPER;
    const float a0 = coefs[lane],       a1 = coefs[64 + lane];
    const float c0 = coefs[128 + lane], c1 = coefs[192 + lane];
    const float t0 = coefs[256 + lane], t1 = coefs[320 + lane];

    for (int i = tid; i < NPER; i += 1024) cmap_s[i] = cmap[obase + i];

    // A: scores, one wave per node
    for (int i = w; i < NCUR; i += 16) {
        const float* row = gcn + (size_t)(nb + i) * 128;
        float h0 = fmaxf(a0 * row[lane] + c0, 0.f);
        float h1 = fmaxf(a1 * row[64 + lane] + c1, 0.f);
        float p  = h0 * t0 + h1 * t1;
#pragma unroll
        for (int off = 32; off > 0; off >>= 1) p += __shfl_down(p, off);
        if (lane == 0) score_s[i] = tanhf(p);
    }
    __syncthreads();

    // B: composite keys
    for (int i = tid; i < NCUR; i += 1024) {
        unsigned u   = __float_as_uint(score_s[i]);
        unsigned key = (u & 0x80000000u) ? ~u : (u | 0x80000000u);
        key_s[i] = ((unsigned long long)key << 32) |
                   (unsigned long long)(0xFFFFFFFFu - (unsigned)i);
    }
    __syncthreads();

    // C: rank selection
    for (int i = tid; i < NCUR; i += 1024) {
        const unsigned long long ki = key_s[i];
        int r = 0;
#pragma unroll 8
        for (int j = 0; j < NCUR; ++j) r += (key_s[j] > ki) ? 1 : 0;
        o2n_s[i] = (r < KK) ? (short)r : (short)-1;
        if (r < KK) n2o_s[r] = (unsigned short)i;
    }
    __syncthreads();

    // D: gating + newx + readout partials
    float mx0 = -1e30f, mx1 = -1e30f, sm0 = 0.f, sm1 = 0.f;
    for (int j2 = w; j2 < KK; j2 += 16) {
        int old = n2o_s[j2];
        float s = score_s[old];
        const float* row = gcn + (size_t)(nb + old) * 128;
        float h0 = fmaxf(a0 * row[lane] + c0, 0.f) * s;
        float h1 = fmaxf(a1 * row[64 + lane] + c1, 0.f) * s;
        float* orow = newx + (size_t)(g * KK + j2) * 128;
        orow[lane]      = h0;
        orow[64 + lane] = h1;
        mx0 = fmaxf(mx0, h0); mx1 = fmaxf(mx1, h1);
        sm0 += h0; sm1 += h1;
    }
    red2[tid] = make_float2(mx0, mx1);
    __syncthreads();
    if (tid < 64) {
        float m = -1e30f;
#pragma unroll
        for (int w2 = 0; w2 < 16; ++w2) m = fmaxf(m, red2[w2 * 64 + tid].x);
        sread[g * 256 + tid] += m;
    } else if (tid < 128) {
        int l = tid - 64;
        float m = -1e30f;
#pragma unroll
        for (int w2 = 0; w2 < 16; ++w2) m = fmaxf(m, red2[w2 * 64 + l].y);
        sread[g * 256 + tid] += m;
    }
    __syncthreads();
    red2[tid] = make_float2(sm0, sm1);
    __syncthreads();
    if (tid < 64) {
        float sm = 0.f;
#pragma unroll
        for (int w2 = 0; w2 < 16; ++w2) sm += red2[w2 * 64 + tid].x;
        sread[g * 256 + 128 + tid] += sm * (1.0f / KK);
    } else if (tid < 128) {
        int l = tid - 64;
        float sm = 0.f;
#pragma unroll
        for (int w2 = 0; w2 < 16; ++w2) sm += red2[w2 * 64 + l].y;
        sread[g * 256 + 128 + tid] += sm * (1.0f / KK);
    }

    // E: cmap remap + zero bnpart slice
    for (int o = tid; o < NPER; o += 1024) {
        int m = cmap_s[o];
        short nm = (m >= 0) ? o2n_s[m] : (short)-1;
        cmap_s[o] = nm;
        cmap[obase + o] = nm;
    }
    if (tid < 256) bnpart[g * 256 + tid] = 0.f;

    if (!BUILD) return;
    __syncthreads();

    // F: build next layer's CSR
    if (tid < 512) cnt_s[tid] = 0;
    __syncthreads();
    for (int e = tid; e < EPG; e += 1024) {
        int sl = cmap_s[src[ebase + e] - obase];
        int dl = cmap_s[dst[ebase + e] - obase];
        if ((sl | dl) >= 0) atomicAdd(&cnt_s[dl], 1);
    }
    __syncthreads();
    int v = 0, x = 0;
    if (tid < 512) {
        v = cnt_s[tid]; x = v;
#pragma unroll
        for (int d = 1; d < 64; d <<= 1) {
            int y = __shfl_up(x, d);
            if (lane >= d) x += y;
        }
        if (lane == 63) chunksum_s[w] = x;
    }
    __syncthreads();
    if (tid == 0) {
        int acc = 0;
#pragma unroll
        for (int k = 0; k < 8; ++k) { int t = chunksum_s[k]; chunksum_s[k] = acc; acc += t; }
    }
    __syncthreads();
    if (tid < 512) {
        int excl = x - v + chunksum_s[w];
        rowptr_s[tid] = excl; wo_s[tid] = excl;
        if (tid == 511) rowptr_s[512] = excl + v;
    }
    __syncthreads();
    for (int i = tid; i <= 512; i += 1024) rowptr_g[g * 513 + i] = rowptr_s[i];
    for (int e = tid; e < EPG; e += 1024) {
        int sl = cmap_s[src[ebase + e] - obase];
        int dl = cmap_s[dst[ebase + e] - obase];
        if ((sl | dl) >= 0) {
            int pos = atomicAdd(&wo_s[dl], 1);
            csr_g[g * EPG + pos] = (unsigned short)sl;
        }
    }
}

// ---------------------------------------------------------------------------
// final MLP
// ---------------------------------------------------------------------------
__global__ void final_kernel(const float* __restrict__ sread,
                             const float* __restrict__ Wl1,
                             const float* __restrict__ bl1,
                             const float* __restrict__ Wl2,
                             const float* __restrict__ bl2,
                             float* __restrict__ out)
{
    __shared__ float s_s[256];
    __shared__ float hid_s[128];
    int g = blockIdx.x, t = threadIdx.x;
    s_s[t]       = sread[g * 256 + t];
    s_s[128 + t] = sread[g * 256 + 128 + t];
    __syncthreads();
    float acc = bl1[t];
    for (int i = 0; i < 256; ++i) acc += s_s[i] * Wl1[i * 128 + t];
    hid_s[t] = fmaxf(acc, 0.f);
    __syncthreads();
    if (t < 2) {
        float o = bl2[t];
        for (int j = 0; j < 128; ++j) o += hid_s[j] * Wl2[j * 2 + t];
        out[g * 2 + t] = o;
    }
}

// ---------------------------------------------------------------------------
extern "C" void kernel_launch(void* const* d_in, const int* in_sizes, int n_in,
                              void* d_out, int out_size, void* d_ws, size_t ws_size,
                              hipStream_t stream)
{
    const float* x    = (const float*)d_in[0];
    const int*   ei   = (const int*)d_in[1];
    const float* Wp   = (const float*)d_in[3];
    const float* bp   = (const float*)d_in[4];
    const float* W1   = (const float*)d_in[5];
    const float* b1   = (const float*)d_in[6];
    const float* g1   = (const float*)d_in[7];
    const float* be1  = (const float*)d_in[8];
    const float* att1 = (const float*)d_in[9];
    const float* W2   = (const float*)d_in[10];
    const float* b2   = (const float*)d_in[11];
    const float* g2   = (const float*)d_in[12];
    const float* be2  = (const float*)d_in[13];
    const float* att2 = (const float*)d_in[14];
    const float* W3   = (const float*)d_in[15];
    const float* b3   = (const float*)d_in[16];
    const float* g3   = (const float*)d_in[17];
    const float* be3  = (const float*)d_in[18];
    const float* att3 = (const float*)d_in[19];
    const float* Wl1  = (const float*)d_in[20];
    const float* bl1  = (const float*)d_in[21];
    const float* Wl2  = (const float*)d_in[22];
    const float* bl2  = (const float*)d_in[23];
    float* out = (float*)d_out;

    const int* srcp = ei;
    const int* dstp = ei + E_TOT;

    char* ws = (char*)d_ws;
    float*          bufA   = (float*)ws;                      // 33,554,432 B
    float*          bufB   = (float*)(ws + 33554432);         // 33,554,432 B
    unsigned short* csr    = (unsigned short*)(ws + 67108864);//  2,097,152 B
    int*            rowptr = (int*)  (ws + 69206016);         //    262,656 B
    float*          bnpart = (float*)(ws + 69468672);         //    131,072 B
    short*          cmap   = (short*)(ws + 69599744);         //    131,072 B
    float*          sread  = (float*)(ws + 69730816);         //    131,072 B
    float*          coefs  = (float*)(ws + 69861888);         //      1,536 B

    init_kernel<<<256, 256, 0, stream>>>(cmap, sread, bnpart);
    csr_build0<<<G, 512, 0, stream>>>(srcp, dstp, csr, rowptr);

    // h0 = relu(x @ Wp + bp)
    gemm_kernel<INC, true><<<512, 256, 0, stream>>>(x, Wp, bp, bufA, NTOT);

    // ---- layer 1 ----
    gemm_kernel<128, false><<<512, 256, 0, stream>>>(bufA, W1, nullptr, bufB, NTOT);
    gather_kernel<512><<<dim3(G, 8), 256, 0, stream>>>(bufB, csr, rowptr, b1, bufA, bnpart);
    bnfin_kernel<<<1, 1024, 0, stream>>>(bnpart, (float)NTOT, g1, be1, att1, coefs);
    pool_kernel<512, KP1, true><<<G, 1024, 0, stream>>>(bufA, coefs, bufB, cmap, sread, bnpart,
                                                        srcp, dstp, csr, rowptr);

    // ---- layer 2 ----  (nodes: G*KP1 = 52480)
    gemm_kernel<128, false><<<410, 256, 0, stream>>>(bufB, W2, nullptr, bufA, G * KP1);
    gather_kernel<KP1><<<dim3(G, 8), 256, 0, stream>>>(bufA, csr, rowptr, b2, bufB, bnpart);
    bnfin_kernel<<<1, 1024, 0, stream>>>(bnpart, (float)(G * KP1), g2, be2, att2, coefs);
    pool_kernel<KP1, KP2, true><<<G, 1024, 0, stream>>>(bufB, coefs, bufA, cmap, sread, bnpart,
                                                        srcp, dstp, csr, rowptr);

    // ---- layer 3 ----  (nodes: G*KP2 = 41984)
    gemm_kernel<128, false><<<328, 256, 0, stream>>>(bufA, W3, nullptr, bufB, G * KP2);
    gather_kernel<KP2><<<dim3(G, 8), 256, 0, stream>>>(bufB, csr, rowptr, b3, bufA, bnpart);
    bnfin_kernel<<<1, 1024, 0, stream>>>(bnpart, (float)(G * KP2), g3, be3, att3, coefs);
    pool_kernel<KP2, KP3, false><<<G, 1024, 0, stream>>>(bufA, coefs, bufB, cmap, sread, bnpart,
                                                         srcp, dstp, csr, rowptr);

    final_kernel<<<G, 128, 0, stream>>>(sread, Wl1, bl1, Wl2, bl2, out);
}